// Round 2
// baseline (1860.313 us; speedup 1.0000x reference)
//
#include <hip/hip_runtime.h>
#include <hip/hip_bf16.h>
#include <math.h>

// Problem constants (reference: N=10000, D=512, k=30 -> k+1=31 neighbors incl. self)
#define NN 10000
#define DD 512
#define KK 31
#define NC 34               // candidates kept per row for f64 rescore
#define EDGES (NN * KK)     // 310000

// ---------------------------------------------------------------------------
// Kernel 1: row L2-normalize x -> xn (f32), plus f64 inverse norm per row
// (matches the np-f64 reference's normalization for the rescore pass).
// One block per row, 256 threads, 2 elements/thread.
// ---------------------------------------------------------------------------
__global__ __launch_bounds__(256) void normalize_rows(const float* __restrict__ x,
                                                      float* __restrict__ xn,
                                                      double* __restrict__ invn) {
    const int row = blockIdx.x;
    const int tid = threadIdx.x;
    const float* xr = x + (size_t)row * DD;
    const float v0 = xr[tid];
    const float v1 = xr[tid + 256];
    double ss = (double)v0 * (double)v0 + (double)v1 * (double)v1;
    #pragma unroll
    for (int off = 32; off > 0; off >>= 1) ss += __shfl_down(ss, off);
    __shared__ double wsum[4];
    __shared__ double sinv;
    if ((tid & 63) == 0) wsum[tid >> 6] = ss;
    __syncthreads();
    if (tid == 0) {
        const double tot = wsum[0] + wsum[1] + wsum[2] + wsum[3];
        const double iv = 1.0 / sqrt(tot);
        invn[row] = iv;
        sinv = iv;
    }
    __syncthreads();
    const float nv = (float)sinv;
    xn[(size_t)row * DD + tid] = v0 * nv;
    xn[(size_t)row * DD + tid + 256] = v1 * nv;
}

// ---------------------------------------------------------------------------
// Kernel 2: sims = xn * xn^T  (f32 vector-FMA tiled GEMM, 128x128 tile, BK=32,
// 256 threads, 8x8 per thread).  Writes into d_out used as sims scratch.
// f32 noise here only affects CANDIDATE selection; top-34 + f64 rescore below
// makes the final top-31 set exact.
// ---------------------------------------------------------------------------
#define TILE 128
#define BK 32

__global__ __launch_bounds__(256) void gemm_xxt(const float* __restrict__ xn,
                                                float* __restrict__ out) {
    __shared__ float As[BK][TILE + 4];
    __shared__ float Bs[BK][TILE + 4];
    const int bi = blockIdx.y, bj = blockIdx.x;
    const int row0 = bi * TILE, col0 = bj * TILE;
    const int tid = threadIdx.x;
    const int tx = tid & 15, ty = tid >> 4;

    float acc[8][8];
    #pragma unroll
    for (int i = 0; i < 8; ++i)
        #pragma unroll
        for (int j = 0; j < 8; ++j) acc[i][j] = 0.f;

    const int kq = tid & 7;   // which float4 within the 32-float K slab
    const int rr = tid >> 3;  // 0..31

    for (int k0 = 0; k0 < DD; k0 += BK) {
        #pragma unroll
        for (int p = 0; p < 4; ++p) {
            const int r = rr + p * 32;
            const int gr = row0 + r;
            const int gc = col0 + r;
            float4 av = make_float4(0.f, 0.f, 0.f, 0.f);
            float4 bv = make_float4(0.f, 0.f, 0.f, 0.f);
            if (gr < NN) av = *(const float4*)(xn + (size_t)gr * DD + k0 + kq * 4);
            if (gc < NN) bv = *(const float4*)(xn + (size_t)gc * DD + k0 + kq * 4);
            As[kq * 4 + 0][r] = av.x; As[kq * 4 + 1][r] = av.y;
            As[kq * 4 + 2][r] = av.z; As[kq * 4 + 3][r] = av.w;
            Bs[kq * 4 + 0][r] = bv.x; Bs[kq * 4 + 1][r] = bv.y;
            Bs[kq * 4 + 2][r] = bv.z; Bs[kq * 4 + 3][r] = bv.w;
        }
        __syncthreads();
        #pragma unroll
        for (int k = 0; k < BK; ++k) {
            const float4 alo = *(const float4*)&As[k][ty * 4];
            const float4 ahi = *(const float4*)&As[k][64 + ty * 4];
            const float4 blo = *(const float4*)&Bs[k][tx * 4];
            const float4 bhi = *(const float4*)&Bs[k][64 + tx * 4];
            const float a[8] = {alo.x, alo.y, alo.z, alo.w, ahi.x, ahi.y, ahi.z, ahi.w};
            const float b[8] = {blo.x, blo.y, blo.z, blo.w, bhi.x, bhi.y, bhi.z, bhi.w};
            #pragma unroll
            for (int i = 0; i < 8; ++i)
                #pragma unroll
                for (int j = 0; j < 8; ++j)
                    acc[i][j] = fmaf(a[i], b[j], acc[i][j]);
        }
        __syncthreads();
    }

    #pragma unroll
    for (int i = 0; i < 8; ++i) {
        const int r = (i < 4) ? (ty * 4 + i) : (64 + ty * 4 + (i - 4));
        const int gr = row0 + r;
        if (gr >= NN) continue;
        #pragma unroll
        for (int jq = 0; jq < 2; ++jq) {
            const int c = (jq == 0) ? (tx * 4) : (64 + tx * 4);
            const int gc = col0 + c;
            float4 v = make_float4(acc[i][jq * 4 + 0], acc[i][jq * 4 + 1],
                                   acc[i][jq * 4 + 2], acc[i][jq * 4 + 3]);
            if (gc + 3 < NN) {
                *(float4*)(out + (size_t)gr * NN + gc) = v;
            } else {
                const float vv[4] = {v.x, v.y, v.z, v.w};
                #pragma unroll
                for (int t = 0; t < 4; ++t)
                    if (gc + t < NN) out[(size_t)gr * NN + gc + t] = vv[t];
            }
        }
    }
}

// ---------------------------------------------------------------------------
// Kernel 3: per-row top-34 CANDIDATES (values desc, tie -> smaller index).
// One 256-thread block per row; 40 register candidates/thread; 34 rounds of
// block argmax over packed u64 keys; winner rescans its registers.
// ---------------------------------------------------------------------------
__global__ __launch_bounds__(256) void topk_rows(const float* __restrict__ sims,
                                                 int* __restrict__ cinds) {
    const int row = blockIdx.x;
    const int tid = threadIdx.x;
    const float* s = sims + (size_t)row * NN;

    float cand[40];
    #pragma unroll
    for (int p = 0; p < 40; ++p) {
        const int j = tid + p * 256;
        cand[p] = (j < NN) ? s[j] : -INFINITY;
    }
    float bestv = -INFINITY;
    int bestp = 0;
    #pragma unroll
    for (int p = 0; p < 40; ++p)
        if (cand[p] > bestv) { bestv = cand[p]; bestp = p; }

    __shared__ unsigned long long wbest[4];
    __shared__ unsigned long long gbest_sh;

    for (int r = 0; r < NC; ++r) {
        unsigned vb = __float_as_uint(bestv);
        vb = (vb & 0x80000000u) ? ~vb : (vb | 0x80000000u);
        const unsigned j = (unsigned)(tid + bestp * 256);
        unsigned long long key =
            ((unsigned long long)vb << 32) | (unsigned long long)(0xFFFFFFFFu - j);
        #pragma unroll
        for (int off = 32; off > 0; off >>= 1) {
            const unsigned long long o = __shfl_down(key, off);
            if (o > key) key = o;
        }
        if ((tid & 63) == 0) wbest[tid >> 6] = key;
        __syncthreads();
        if (tid == 0) {
            unsigned long long g = wbest[0];
            #pragma unroll
            for (int w = 1; w < 4; ++w)
                if (wbest[w] > g) g = wbest[w];
            gbest_sh = g;
        }
        __syncthreads();
        const unsigned long long g = gbest_sh;
        const unsigned jwin = 0xFFFFFFFFu - (unsigned)(g & 0xFFFFFFFFull);

        if (tid == 0) cinds[(size_t)row * NC + r] = (int)jwin;

        if ((jwin & 255u) == (unsigned)tid) {
            const int pwin = (int)(jwin >> 8);
            #pragma unroll
            for (int p = 0; p < 40; ++p)
                if (p == pwin) cand[p] = -INFINITY;
            bestv = -INFINITY; bestp = 0;
            #pragma unroll
            for (int p = 0; p < 40; ++p)
                if (cand[p] > bestv) { bestv = cand[p]; bestp = p; }
        }
        __syncthreads();
    }
}

// ---------------------------------------------------------------------------
// Kernel 4: f64 rescore of the 34 candidates per row; exact (vs np-f64 ref)
// re-ranking; emits the final 31 (vals f32, inds) + norm_row.
// One block per row: 4 waves each score candidates in stride-4; wave 0 ranks.
// ---------------------------------------------------------------------------
__global__ __launch_bounds__(256) void rescore_topk(const float* __restrict__ x,
                                                    const double* __restrict__ invn,
                                                    const int* __restrict__ cinds,
                                                    float* __restrict__ vals,
                                                    int* __restrict__ inds,
                                                    float* __restrict__ norm_row) {
    const int row = blockIdx.x;
    const int tid = threadIdx.x;
    const int lane = tid & 63;
    const int wave = tid >> 6;

    __shared__ double scand[NC];

    const float* xr = x + (size_t)row * DD;
    float a[8];
    #pragma unroll
    for (int t = 0; t < 8; ++t) a[t] = xr[lane * 8 + t];
    const double ir = invn[row];

    for (int c = wave; c < NC; c += 4) {
        const int j = cinds[(size_t)row * NC + c];
        const float* xj = x + (size_t)j * DD;
        double p = 0.0;
        #pragma unroll
        for (int t = 0; t < 8; ++t)
            p = fma((double)a[t], (double)xj[lane * 8 + t], p);
        #pragma unroll
        for (int off = 32; off > 0; off >>= 1)
            p += __shfl_down(p, off);
        if (lane == 0) scand[c] = p * ir * invn[j];
    }
    __syncthreads();

    if (wave == 0) {
        double v = -1e300;
        int idx = 0x7FFFFFFF;
        if (lane < NC) {
            v = scand[lane];
            idx = cinds[(size_t)row * NC + lane];
        }
        int rank = 0;
        for (int m = 0; m < NC; ++m) {
            const double vm = scand[m];
            const int im = cinds[(size_t)row * NC + m];
            if (vm > v || (vm == v && im < idx)) ++rank;
        }
        float contrib = 0.f;
        if (lane < NC && rank < KK) {
            const float vf = (float)v;
            vals[(size_t)row * KK + rank] = vf;
            inds[(size_t)row * KK + rank] = idx;
            contrib = vf;
        }
        #pragma unroll
        for (int off = 32; off > 0; off >>= 1)
            contrib += __shfl_down(contrib, off);
        if (lane == 0) norm_row[row] = contrib;
    }
}

// ---------------------------------------------------------------------------
// Edge-chain kernels (310k edges each, trivial cost)
// ---------------------------------------------------------------------------
__global__ void scatter_norm_col(const float* __restrict__ vals,
                                 const int* __restrict__ inds,
                                 float* __restrict__ norm_col) {
    const int e = blockIdx.x * 256 + threadIdx.x;
    if (e >= EDGES) return;
    atomicAdd(&norm_col[inds[e]], vals[e]);
}

__global__ void values_and_deg(const float* __restrict__ vals,
                               const int* __restrict__ inds,
                               const float* __restrict__ norm_row,
                               const float* __restrict__ norm_col,
                               float* __restrict__ vrelu,
                               float* __restrict__ deg) {
    const int e = blockIdx.x * 256 + threadIdx.x;
    if (e >= EDGES) return;
    const int i = e / KK;
    const int j = inds[e];
    const float ni = norm_row[i] + norm_col[i];
    const float nj = norm_row[j] + norm_col[j];
    float v = vals[e] * (1.0f / sqrtf(ni)) * (1.0f / sqrtf(nj));
    if (v != v) v = 0.f;           // NaN -> 0
    v = fmaxf(v, 0.f);             // relu (both symmetric copies)
    vrelu[e] = v;
    atomicAdd(&deg[i], v);         // rows_ copy 1
    atomicAdd(&deg[j], v);         // rows_ copy 2
}

__global__ void compute_dinv(const float* __restrict__ deg, float* __restrict__ dinv) {
    const int i = blockIdx.x * 256 + threadIdx.x;
    if (i >= NN) return;
    const float d = deg[i];
    float di = 1.0f / sqrtf(d);
    if (!isfinite(di)) di = 0.f;   // deg==0 -> inf -> 0
    dinv[i] = di;
}

__global__ void scatter_out(const float* __restrict__ vrelu,
                            const int* __restrict__ inds,
                            const float* __restrict__ dinv,
                            float* __restrict__ out) {
    const int e = blockIdx.x * 256 + threadIdx.x;
    if (e >= EDGES) return;
    const int i = e / KK;
    const int j = inds[e];
    const float nv = vrelu[e] * dinv[i] * dinv[j];
    atomicAdd(&out[(size_t)i * NN + j], nv);
    atomicAdd(&out[(size_t)j * NN + i], nv);
}

// ---------------------------------------------------------------------------
// Launch
// ---------------------------------------------------------------------------
extern "C" void kernel_launch(void* const* d_in, const int* in_sizes, int n_in,
                              void* d_out, int out_size, void* d_ws, size_t ws_size,
                              hipStream_t stream) {
    const float* x = (const float*)d_in[0];
    float* out = (float*)d_out;
    float* ws = (float*)d_ws;

    // workspace layout (f32-element offsets), total ~27.2 MB
    float*  xn       = ws;                        // 5,120,000 f32
    double* invn     = (double*)(ws + 5120000);   //    10,000 f64 (byte off 20,480,000 — 8B aligned)
    int*    cinds    = (int*)(ws + 5140000);      //   340,000 int
    float*  vals     = ws + 5480000;              //   310,000 f32
    int*    inds     = (int*)(ws + 5790000);      //   310,000 int
    float*  norm_row = ws + 6100000;              //    10,000
    float*  norm_col = ws + 6110000;              //    10,000
    float*  deg      = ws + 6120000;              //    10,000
    float*  dinv     = ws + 6130000;              //    10,000
    float*  vrelu    = ws + 6140000;              //   310,000

    // 1) row normalize (f32 vectors + f64 inverse norms)
    normalize_rows<<<NN, 256, 0, stream>>>(x, xn, invn);

    // 2) sims = xn xn^T into d_out (scratch)
    dim3 gg((NN + TILE - 1) / TILE, (NN + TILE - 1) / TILE);
    gemm_xxt<<<gg, 256, 0, stream>>>(xn, out);

    // 3) per-row top-34 candidates (f32)
    topk_rows<<<NN, 256, 0, stream>>>(out, cinds);

    // 4) exact f64 rescore + final top-31 selection
    rescore_topk<<<NN, 256, 0, stream>>>(x, invn, cinds, vals, inds, norm_row);

    // 5) edge normalization chain
    hipMemsetAsync(norm_col, 0, NN * sizeof(float), stream);
    hipMemsetAsync(deg, 0, NN * sizeof(float), stream);
    const int eb = (EDGES + 255) / 256;
    scatter_norm_col<<<eb, 256, 0, stream>>>(vals, inds, norm_col);
    values_and_deg<<<eb, 256, 0, stream>>>(vals, inds, norm_row, norm_col, vrelu, deg);
    compute_dinv<<<(NN + 255) / 256, 256, 0, stream>>>(deg, dinv);

    // 6) zero the dense output, then scatter symmetric normalized edges
    hipMemsetAsync(out, 0, (size_t)NN * NN * sizeof(float), stream);
    scatter_out<<<eb, 256, 0, stream>>>(vrelu, inds, dinv, out);
}

// Round 3
// 942.433 us; speedup vs baseline: 1.9739x; 1.9739x over previous
//
#include <hip/hip_runtime.h>
#include <hip/hip_bf16.h>
#include <math.h>

// Problem constants (reference: N=10000, D=512, k=30 -> k+1=31 neighbors incl. self)
#define NN 10000
#define DD 512
#define KK 31
#define NC 34               // candidates kept per row for f64 rescore
#define EDGES (NN * KK)     // 310000

typedef __attribute__((ext_vector_type(8))) short short8v;   // 8 bf16 (4 VGPRs)
typedef __attribute__((ext_vector_type(4))) float f32x4;     // MFMA C/D frag

__device__ inline unsigned short f32_to_bf16_rne(float f) {
    unsigned u = __float_as_uint(f);
    u += 0x7FFFu + ((u >> 16) & 1u);   // round-to-nearest-even
    return (unsigned short)(u >> 16);
}

// ---------------------------------------------------------------------------
// Kernel 1: row L2-normalize x; emit split-bf16 (hi + lo) of xn and the f64
// inverse norm (used by the exact rescore pass).
// ---------------------------------------------------------------------------
__global__ __launch_bounds__(256) void normalize_rows(const float* __restrict__ x,
                                                      unsigned short* __restrict__ xh,
                                                      unsigned short* __restrict__ xl,
                                                      double* __restrict__ invn) {
    const int row = blockIdx.x;
    const int tid = threadIdx.x;
    const float* xr = x + (size_t)row * DD;
    const float v0 = xr[tid];
    const float v1 = xr[tid + 256];
    double ss = (double)v0 * (double)v0 + (double)v1 * (double)v1;
    #pragma unroll
    for (int off = 32; off > 0; off >>= 1) ss += __shfl_down(ss, off);
    __shared__ double wsum[4];
    __shared__ double sinv;
    if ((tid & 63) == 0) wsum[tid >> 6] = ss;
    __syncthreads();
    if (tid == 0) {
        const double iv = 1.0 / sqrt(wsum[0] + wsum[1] + wsum[2] + wsum[3]);
        invn[row] = iv;
        sinv = iv;
    }
    __syncthreads();
    const float nv = (float)sinv;
    #pragma unroll
    for (int e = 0; e < 2; ++e) {
        const float v = (e == 0 ? v0 : v1) * nv;
        const unsigned short h = f32_to_bf16_rne(v);
        const float fh = __uint_as_float(((unsigned)h) << 16);
        const unsigned short lo = f32_to_bf16_rne(v - fh);
        const size_t idx = (size_t)row * DD + tid + e * 256;
        xh[idx] = h;
        xl[idx] = lo;
    }
}

// ---------------------------------------------------------------------------
// Kernel 2: sims = xn xn^T via split-bf16 MFMA:
//   sims ~= hi*hi^T + hi*lo^T + lo*hi^T     (error ~3e-7, rescore-safe)
// 128x128 tile, BK=64, 4 waves (2x2), 64x64 per wave, mfma_f32_16x16x32_bf16.
// LDS tiles [128][64] bf16 with XOR swizzle (kchunk ^ (row&7)) on the 16B slot
// to kill the 16-way bank conflict of the 128B-stride fragment read.
// ---------------------------------------------------------------------------
#define TILE 128
#define BKK 64

__global__ __launch_bounds__(256) void gemm_mfma(const unsigned short* __restrict__ hi,
                                                 const unsigned short* __restrict__ lo,
                                                 float* __restrict__ out) {
    // 4 tiles: A_hi, A_lo, B_hi, B_lo — each 128x64 bf16 = 16KB, total 64KB
    __shared__ unsigned short lds[4][TILE * BKK];

    const int bi = blockIdx.y, bj = blockIdx.x;
    const int row0 = bi * TILE, col0 = bj * TILE;
    const int tid = threadIdx.x;
    const int l = tid & 63, wid = tid >> 6;
    const int wm = wid >> 1, wn = wid & 1;       // 2x2 wave grid
    const int c = l & 15, g = l >> 4;            // frag col / k-group

    f32x4 acc[4][4];
    #pragma unroll
    for (int i = 0; i < 4; ++i)
        #pragma unroll
        for (int j = 0; j < 4; ++j) acc[i][j] = (f32x4){0.f, 0.f, 0.f, 0.f};

    for (int k0 = 0; k0 < DD; k0 += BKK) {
        // ---- stage: 1024 16B-slots per tile, 256 threads x 4 iters ----
        #pragma unroll
        for (int i = 0; i < 4; ++i) {
            const int s = i * 256 + tid;         // slot id
            const int r = s >> 3;                // row in tile (0..127)
            const int cs = s & 7;                // 16B k-chunk (0..7)
            const int ldso = r * BKK + ((cs ^ (r & 7)) * 8);  // swizzled, ushort units
            const int gar = row0 + r, gbr = col0 + r;
            short8v ah = (short8v)0, al = (short8v)0, bh = (short8v)0, bl = (short8v)0;
            const size_t goff = (size_t)(k0 + cs * 8);
            if (gar < NN) {
                ah = *(const short8v*)(hi + (size_t)gar * DD + goff);
                al = *(const short8v*)(lo + (size_t)gar * DD + goff);
            }
            if (gbr < NN) {
                bh = *(const short8v*)(hi + (size_t)gbr * DD + goff);
                bl = *(const short8v*)(lo + (size_t)gbr * DD + goff);
            }
            *(short8v*)(&lds[0][ldso]) = ah;
            *(short8v*)(&lds[1][ldso]) = al;
            *(short8v*)(&lds[2][ldso]) = bh;
            *(short8v*)(&lds[3][ldso]) = bl;
        }
        __syncthreads();

        // ---- compute: 2 k-subtiles of 32 ----
        #pragma unroll
        for (int ks = 0; ks < 2; ++ks) {
            short8v a_hi[4], a_lo[4], b_hi[4], b_lo[4];
            const int kc = ks * 4 + g;           // k-chunk 0..7
            #pragma unroll
            for (int fm = 0; fm < 4; ++fm) {
                const int r = wm * 64 + fm * 16 + c;
                const int off = r * BKK + ((kc ^ (r & 7)) * 8);
                a_hi[fm] = *(const short8v*)(&lds[0][off]);
                a_lo[fm] = *(const short8v*)(&lds[1][off]);
            }
            #pragma unroll
            for (int fn = 0; fn < 4; ++fn) {
                const int r = wn * 64 + fn * 16 + c;
                const int off = r * BKK + ((kc ^ (r & 7)) * 8);
                b_hi[fn] = *(const short8v*)(&lds[2][off]);
                b_lo[fn] = *(const short8v*)(&lds[3][off]);
            }
            #pragma unroll
            for (int fm = 0; fm < 4; ++fm)
                #pragma unroll
                for (int fn = 0; fn < 4; ++fn) {
                    acc[fm][fn] = __builtin_amdgcn_mfma_f32_16x16x32_bf16(
                        a_hi[fm], b_hi[fn], acc[fm][fn], 0, 0, 0);
                    acc[fm][fn] = __builtin_amdgcn_mfma_f32_16x16x32_bf16(
                        a_hi[fm], b_lo[fn], acc[fm][fn], 0, 0, 0);
                    acc[fm][fn] = __builtin_amdgcn_mfma_f32_16x16x32_bf16(
                        a_lo[fm], b_hi[fn], acc[fm][fn], 0, 0, 0);
                }
        }
        __syncthreads();
    }

    // ---- epilogue: C layout col = l&15, row = (l>>4)*4 + reg ----
    #pragma unroll
    for (int fm = 0; fm < 4; ++fm) {
        #pragma unroll
        for (int fn = 0; fn < 4; ++fn) {
            const int gc = col0 + wn * 64 + fn * 16 + c;
            if (gc >= NN) continue;
            #pragma unroll
            for (int r = 0; r < 4; ++r) {
                const int gr = row0 + wm * 64 + fm * 16 + g * 4 + r;
                if (gr < NN) out[(size_t)gr * NN + gc] = acc[fm][fn][r];
            }
        }
    }
}

// ---------------------------------------------------------------------------
// Kernel 3: per-row top-34 CANDIDATES (values desc, tie -> smaller index).
// One 256-thread block per row; 40 register candidates/thread; 34 rounds of
// block argmax over packed u64 keys; winner rescans its registers.
// ---------------------------------------------------------------------------
__global__ __launch_bounds__(256) void topk_rows(const float* __restrict__ sims,
                                                 int* __restrict__ cinds) {
    const int row = blockIdx.x;
    const int tid = threadIdx.x;
    const float* s = sims + (size_t)row * NN;

    float cand[40];
    #pragma unroll
    for (int p = 0; p < 40; ++p) {
        const int j = tid + p * 256;
        cand[p] = (j < NN) ? s[j] : -INFINITY;
    }
    float bestv = -INFINITY;
    int bestp = 0;
    #pragma unroll
    for (int p = 0; p < 40; ++p)
        if (cand[p] > bestv) { bestv = cand[p]; bestp = p; }

    __shared__ unsigned long long wbest[4];
    __shared__ unsigned long long gbest_sh;

    for (int r = 0; r < NC; ++r) {
        unsigned vb = __float_as_uint(bestv);
        vb = (vb & 0x80000000u) ? ~vb : (vb | 0x80000000u);
        const unsigned j = (unsigned)(tid + bestp * 256);
        unsigned long long key =
            ((unsigned long long)vb << 32) | (unsigned long long)(0xFFFFFFFFu - j);
        #pragma unroll
        for (int off = 32; off > 0; off >>= 1) {
            const unsigned long long o = __shfl_down(key, off);
            if (o > key) key = o;
        }
        if ((tid & 63) == 0) wbest[tid >> 6] = key;
        __syncthreads();
        if (tid == 0) {
            unsigned long long gg = wbest[0];
            #pragma unroll
            for (int w = 1; w < 4; ++w)
                if (wbest[w] > gg) gg = wbest[w];
            gbest_sh = gg;
        }
        __syncthreads();
        const unsigned long long gg = gbest_sh;
        const unsigned jwin = 0xFFFFFFFFu - (unsigned)(gg & 0xFFFFFFFFull);

        if (tid == 0) cinds[(size_t)row * NC + r] = (int)jwin;

        if ((jwin & 255u) == (unsigned)tid) {
            const int pwin = (int)(jwin >> 8);
            #pragma unroll
            for (int p = 0; p < 40; ++p)
                if (p == pwin) cand[p] = -INFINITY;
            bestv = -INFINITY; bestp = 0;
            #pragma unroll
            for (int p = 0; p < 40; ++p)
                if (cand[p] > bestv) { bestv = cand[p]; bestp = p; }
        }
        __syncthreads();
    }
}

// ---------------------------------------------------------------------------
// Kernel 4: f64 rescore of the 34 candidates per row; exact re-ranking;
// emits the final 31 (vals f32, inds) + norm_row.
// ---------------------------------------------------------------------------
__global__ __launch_bounds__(256) void rescore_topk(const float* __restrict__ x,
                                                    const double* __restrict__ invn,
                                                    const int* __restrict__ cinds,
                                                    float* __restrict__ vals,
                                                    int* __restrict__ inds,
                                                    float* __restrict__ norm_row) {
    const int row = blockIdx.x;
    const int tid = threadIdx.x;
    const int lane = tid & 63;
    const int wave = tid >> 6;

    __shared__ double scand[NC];

    const float* xr = x + (size_t)row * DD;
    float a[8];
    #pragma unroll
    for (int t = 0; t < 8; ++t) a[t] = xr[lane * 8 + t];
    const double ir = invn[row];

    for (int cc = wave; cc < NC; cc += 4) {
        const int j = cinds[(size_t)row * NC + cc];
        const float* xj = x + (size_t)j * DD;
        double p = 0.0;
        #pragma unroll
        for (int t = 0; t < 8; ++t)
            p = fma((double)a[t], (double)xj[lane * 8 + t], p);
        #pragma unroll
        for (int off = 32; off > 0; off >>= 1)
            p += __shfl_down(p, off);
        if (lane == 0) scand[cc] = p * ir * invn[j];
    }
    __syncthreads();

    if (wave == 0) {
        double v = -1e300;
        int idx = 0x7FFFFFFF;
        if (lane < NC) {
            v = scand[lane];
            idx = cinds[(size_t)row * NC + lane];
        }
        int rank = 0;
        for (int m = 0; m < NC; ++m) {
            const double vm = scand[m];
            const int im = cinds[(size_t)row * NC + m];
            if (vm > v || (vm == v && im < idx)) ++rank;
        }
        float contrib = 0.f;
        if (lane < NC && rank < KK) {
            const float vf = (float)v;
            vals[(size_t)row * KK + rank] = vf;
            inds[(size_t)row * KK + rank] = idx;
            contrib = vf;
        }
        #pragma unroll
        for (int off = 32; off > 0; off >>= 1)
            contrib += __shfl_down(contrib, off);
        if (lane == 0) norm_row[row] = contrib;
    }
}

// ---------------------------------------------------------------------------
// Edge-chain kernels (310k edges each, trivial cost)
// ---------------------------------------------------------------------------
__global__ void scatter_norm_col(const float* __restrict__ vals,
                                 const int* __restrict__ inds,
                                 float* __restrict__ norm_col) {
    const int e = blockIdx.x * 256 + threadIdx.x;
    if (e >= EDGES) return;
    atomicAdd(&norm_col[inds[e]], vals[e]);
}

__global__ void values_and_deg(const float* __restrict__ vals,
                               const int* __restrict__ inds,
                               const float* __restrict__ norm_row,
                               const float* __restrict__ norm_col,
                               float* __restrict__ vrelu,
                               float* __restrict__ deg) {
    const int e = blockIdx.x * 256 + threadIdx.x;
    if (e >= EDGES) return;
    const int i = e / KK;
    const int j = inds[e];
    const float ni = norm_row[i] + norm_col[i];
    const float nj = norm_row[j] + norm_col[j];
    float v = vals[e] * (1.0f / sqrtf(ni)) * (1.0f / sqrtf(nj));
    if (v != v) v = 0.f;           // NaN -> 0
    v = fmaxf(v, 0.f);             // relu (both symmetric copies)
    vrelu[e] = v;
    atomicAdd(&deg[i], v);
    atomicAdd(&deg[j], v);
}

__global__ void compute_dinv(const float* __restrict__ deg, float* __restrict__ dinv) {
    const int i = blockIdx.x * 256 + threadIdx.x;
    if (i >= NN) return;
    float di = 1.0f / sqrtf(deg[i]);
    if (!isfinite(di)) di = 0.f;
    dinv[i] = di;
}

__global__ void scatter_out(const float* __restrict__ vrelu,
                            const int* __restrict__ inds,
                            const float* __restrict__ dinv,
                            float* __restrict__ out) {
    const int e = blockIdx.x * 256 + threadIdx.x;
    if (e >= EDGES) return;
    const int i = e / KK;
    const int j = inds[e];
    const float nv = vrelu[e] * dinv[i] * dinv[j];
    atomicAdd(&out[(size_t)i * NN + j], nv);
    atomicAdd(&out[(size_t)j * NN + i], nv);
}

// ---------------------------------------------------------------------------
// Launch
// ---------------------------------------------------------------------------
extern "C" void kernel_launch(void* const* d_in, const int* in_sizes, int n_in,
                              void* d_out, int out_size, void* d_ws, size_t ws_size,
                              hipStream_t stream) {
    const float* x = (const float*)d_in[0];
    float* out = (float*)d_out;
    float* ws = (float*)d_ws;

    // workspace layout (f32-element offsets), total ~25.8 MB
    unsigned short* xh   = (unsigned short*)ws;               // 5,120,000 u16 (2.56M f32 slots)
    unsigned short* xl   = (unsigned short*)(ws + 2560000);   // 5,120,000 u16
    double* invn         = (double*)(ws + 5120000);           // 10,000 f64 (20,000 slots)
    int*    cinds        = (int*)(ws + 5140000);              // 340,000
    float*  vals         = ws + 5480000;                      // 310,000
    int*    inds         = (int*)(ws + 5790000);              // 310,000
    float*  norm_row     = ws + 6100000;                      // 10,000
    float*  norm_col     = ws + 6110000;                      // 10,000
    float*  deg          = ws + 6120000;                      // 10,000
    float*  dinv         = ws + 6130000;                      // 10,000
    float*  vrelu        = ws + 6140000;                      // 310,000

    // 1) row normalize -> split-bf16 hi/lo + f64 inv norms
    normalize_rows<<<NN, 256, 0, stream>>>(x, xh, xl, invn);

    // 2) sims into d_out (scratch) via split-bf16 MFMA
    dim3 gg((NN + TILE - 1) / TILE, (NN + TILE - 1) / TILE);
    gemm_mfma<<<gg, 256, 0, stream>>>(xh, xl, out);

    // 3) per-row top-34 candidates (f32)
    topk_rows<<<NN, 256, 0, stream>>>(out, cinds);

    // 4) exact f64 rescore + final top-31 selection
    rescore_topk<<<NN, 256, 0, stream>>>(x, invn, cinds, vals, inds, norm_row);

    // 5) edge normalization chain
    hipMemsetAsync(norm_col, 0, NN * sizeof(float), stream);
    hipMemsetAsync(deg, 0, NN * sizeof(float), stream);
    const int eb = (EDGES + 255) / 256;
    scatter_norm_col<<<eb, 256, 0, stream>>>(vals, inds, norm_col);
    values_and_deg<<<eb, 256, 0, stream>>>(vals, inds, norm_row, norm_col, vrelu, deg);
    compute_dinv<<<(NN + 255) / 256, 256, 0, stream>>>(deg, dinv);

    // 6) zero the dense output, then scatter symmetric normalized edges
    hipMemsetAsync(out, 0, (size_t)NN * NN * sizeof(float), stream);
    scatter_out<<<eb, 256, 0, stream>>>(vrelu, inds, dinv, out);
}

// Round 4
// 790.532 us; speedup vs baseline: 2.3532x; 1.1921x over previous
//
#include <hip/hip_runtime.h>
#include <hip/hip_bf16.h>
#include <math.h>

// Problem constants (reference: N=10000, D=512, k=30 -> k+1=31 neighbors incl. self)
#define NN 10000
#define DD 512
#define KK 31
#define NC 40               // candidates kept per row for f64 rescore (margin vs bf16 noise)
#define EDGES (NN * KK)     // 310000

typedef __attribute__((ext_vector_type(8))) short short8v;   // 8 bf16 (4 VGPRs)
typedef __attribute__((ext_vector_type(4))) float f32x4;     // MFMA C/D frag

__device__ inline unsigned short f32_to_bf16_rne(float f) {
    unsigned u = __float_as_uint(f);
    u += 0x7FFFu + ((u >> 16) & 1u);   // round-to-nearest-even
    return (unsigned short)(u >> 16);
}

// ---------------------------------------------------------------------------
// Kernel 1: row L2-normalize x; emit bf16(xn) and the f64 inverse norm
// (used by the exact rescore pass).
// ---------------------------------------------------------------------------
__global__ __launch_bounds__(256) void normalize_rows(const float* __restrict__ x,
                                                      unsigned short* __restrict__ xh,
                                                      double* __restrict__ invn) {
    const int row = blockIdx.x;
    const int tid = threadIdx.x;
    const float* xr = x + (size_t)row * DD;
    const float v0 = xr[tid];
    const float v1 = xr[tid + 256];
    double ss = (double)v0 * (double)v0 + (double)v1 * (double)v1;
    #pragma unroll
    for (int off = 32; off > 0; off >>= 1) ss += __shfl_down(ss, off);
    __shared__ double wsum[4];
    __shared__ double sinv;
    if ((tid & 63) == 0) wsum[tid >> 6] = ss;
    __syncthreads();
    if (tid == 0) {
        const double iv = 1.0 / sqrt(wsum[0] + wsum[1] + wsum[2] + wsum[3]);
        invn[row] = iv;
        sinv = iv;
    }
    __syncthreads();
    const float nv = (float)sinv;
    xh[(size_t)row * DD + tid]       = f32_to_bf16_rne(v0 * nv);
    xh[(size_t)row * DD + tid + 256] = f32_to_bf16_rne(v1 * nv);
}

// ---------------------------------------------------------------------------
// Kernel 2: sims ~= bf16(xn) * bf16(xn)^T  (error ~1e-4; candidate-safe since
// the f64 rescore of top-40 fixes the final top-31 set exactly).
// 128x128 tile, BK=64, 4 waves (2x2), 64x64 per wave, mfma_f32_16x16x32_bf16.
// LDS [128][64] bf16, XOR swizzle (chunk ^ (row&7)) on 16B slots (bank-conflict
// free, verified 0 in R3).  Bijective XCD-aware block swizzle (m204) for L2
// panel locality (nwg=6241, q=780, r=1).
// ---------------------------------------------------------------------------
#define TILE 128
#define BKK 64
#define GDIM 79   // ceil(10000/128)

__global__ __launch_bounds__(256) void gemm_mfma(const unsigned short* __restrict__ hi,
                                                 float* __restrict__ out) {
    __shared__ unsigned short lds[2][TILE * BKK];   // A-hi, B-hi: 16KB each

    // bijective XCD swizzle: nwg=6241, q=780, r=1
    const int orig = blockIdx.x;
    const int xcd = orig & 7;
    const int pos = orig >> 3;
    const int nw = (xcd < 1 ? xcd * 781 : 781 + (xcd - 1) * 780) + pos;
    const int bi = nw / GDIM, bj = nw % GDIM;

    const int row0 = bi * TILE, col0 = bj * TILE;
    const int tid = threadIdx.x;
    const int l = tid & 63, wid = tid >> 6;
    const int wm = wid >> 1, wn = wid & 1;       // 2x2 wave grid
    const int c = l & 15, g = l >> 4;            // frag col / k-group

    f32x4 acc[4][4];
    #pragma unroll
    for (int i = 0; i < 4; ++i)
        #pragma unroll
        for (int j = 0; j < 4; ++j) acc[i][j] = (f32x4){0.f, 0.f, 0.f, 0.f};

    for (int k0 = 0; k0 < DD; k0 += BKK) {
        // ---- stage: 1024 16B-slots per tile, 256 threads x 4 iters ----
        #pragma unroll
        for (int i = 0; i < 4; ++i) {
            const int s = i * 256 + tid;         // slot id
            const int r = s >> 3;                // row in tile (0..127)
            const int cs = s & 7;                // 16B k-chunk (0..7)
            const int ldso = r * BKK + ((cs ^ (r & 7)) * 8);  // swizzled, ushort units
            const int gar = row0 + r, gbr = col0 + r;
            short8v ah = (short8v)0, bh = (short8v)0;
            const size_t goff = (size_t)(k0 + cs * 8);
            if (gar < NN) ah = *(const short8v*)(hi + (size_t)gar * DD + goff);
            if (gbr < NN) bh = *(const short8v*)(hi + (size_t)gbr * DD + goff);
            *(short8v*)(&lds[0][ldso]) = ah;
            *(short8v*)(&lds[1][ldso]) = bh;
        }
        __syncthreads();

        // ---- compute: 2 k-subtiles of 32 ----
        #pragma unroll
        for (int ks = 0; ks < 2; ++ks) {
            short8v a_hi[4], b_hi[4];
            const int kc = ks * 4 + g;           // k-chunk 0..7
            #pragma unroll
            for (int fm = 0; fm < 4; ++fm) {
                const int r = wm * 64 + fm * 16 + c;
                a_hi[fm] = *(const short8v*)(&lds[0][r * BKK + ((kc ^ (r & 7)) * 8)]);
            }
            #pragma unroll
            for (int fn = 0; fn < 4; ++fn) {
                const int r = wn * 64 + fn * 16 + c;
                b_hi[fn] = *(const short8v*)(&lds[1][r * BKK + ((kc ^ (r & 7)) * 8)]);
            }
            #pragma unroll
            for (int fm = 0; fm < 4; ++fm)
                #pragma unroll
                for (int fn = 0; fn < 4; ++fn)
                    acc[fm][fn] = __builtin_amdgcn_mfma_f32_16x16x32_bf16(
                        a_hi[fm], b_hi[fn], acc[fm][fn], 0, 0, 0);
        }
        __syncthreads();
    }

    // ---- epilogue: C layout col = l&15, row = (l>>4)*4 + reg ----
    #pragma unroll
    for (int fm = 0; fm < 4; ++fm) {
        #pragma unroll
        for (int fn = 0; fn < 4; ++fn) {
            const int gc = col0 + wn * 64 + fn * 16 + c;
            if (gc >= NN) continue;
            #pragma unroll
            for (int r = 0; r < 4; ++r) {
                const int gr = row0 + wm * 64 + fm * 16 + g * 4 + r;
                if (gr < NN) out[(size_t)gr * NN + gc] = acc[fm][fn][r];
            }
        }
    }
}

// ---------------------------------------------------------------------------
// Kernel 3: per-row top-40 CANDIDATES (values desc, tie -> smaller index).
// One 256-thread block per row; 40 register candidates/thread; NC rounds of
// block argmax over packed u64 keys; winner rescans its registers.
// ---------------------------------------------------------------------------
__global__ __launch_bounds__(256) void topk_rows(const float* __restrict__ sims,
                                                 int* __restrict__ cinds) {
    const int row = blockIdx.x;
    const int tid = threadIdx.x;
    const float* s = sims + (size_t)row * NN;

    float cand[40];
    #pragma unroll
    for (int p = 0; p < 40; ++p) {
        const int j = tid + p * 256;
        cand[p] = (j < NN) ? s[j] : -INFINITY;
    }
    float bestv = -INFINITY;
    int bestp = 0;
    #pragma unroll
    for (int p = 0; p < 40; ++p)
        if (cand[p] > bestv) { bestv = cand[p]; bestp = p; }

    __shared__ unsigned long long wbest[4];
    __shared__ unsigned long long gbest_sh;

    for (int r = 0; r < NC; ++r) {
        unsigned vb = __float_as_uint(bestv);
        vb = (vb & 0x80000000u) ? ~vb : (vb | 0x80000000u);
        const unsigned j = (unsigned)(tid + bestp * 256);
        unsigned long long key =
            ((unsigned long long)vb << 32) | (unsigned long long)(0xFFFFFFFFu - j);
        #pragma unroll
        for (int off = 32; off > 0; off >>= 1) {
            const unsigned long long o = __shfl_down(key, off);
            if (o > key) key = o;
        }
        if ((tid & 63) == 0) wbest[tid >> 6] = key;
        __syncthreads();
        if (tid == 0) {
            unsigned long long gg = wbest[0];
            #pragma unroll
            for (int w = 1; w < 4; ++w)
                if (wbest[w] > gg) gg = wbest[w];
            gbest_sh = gg;
        }
        __syncthreads();
        const unsigned long long gg = gbest_sh;
        const unsigned jwin = 0xFFFFFFFFu - (unsigned)(gg & 0xFFFFFFFFull);

        if (tid == 0) cinds[(size_t)row * NC + r] = (int)jwin;

        if ((jwin & 255u) == (unsigned)tid) {
            const int pwin = (int)(jwin >> 8);
            #pragma unroll
            for (int p = 0; p < 40; ++p)
                if (p == pwin) cand[p] = -INFINITY;
            bestv = -INFINITY; bestp = 0;
            #pragma unroll
            for (int p = 0; p < 40; ++p)
                if (cand[p] > bestv) { bestv = cand[p]; bestp = p; }
        }
        __syncthreads();
    }
}

// ---------------------------------------------------------------------------
// Kernel 4: f64 rescore of the NC candidates per row; exact re-ranking;
// emits the final 31 (vals f32, inds) + norm_row (sum of the 31).
// ---------------------------------------------------------------------------
__global__ __launch_bounds__(256) void rescore_topk(const float* __restrict__ x,
                                                    const double* __restrict__ invn,
                                                    const int* __restrict__ cinds,
                                                    float* __restrict__ vals,
                                                    int* __restrict__ inds,
                                                    float* __restrict__ norm_row) {
    const int row = blockIdx.x;
    const int tid = threadIdx.x;
    const int lane = tid & 63;
    const int wave = tid >> 6;

    __shared__ double scand[NC];

    const float* xr = x + (size_t)row * DD;
    float a[8];
    #pragma unroll
    for (int t = 0; t < 8; ++t) a[t] = xr[lane * 8 + t];
    const double ir = invn[row];

    for (int cc = wave; cc < NC; cc += 4) {
        const int j = cinds[(size_t)row * NC + cc];
        const float* xj = x + (size_t)j * DD;
        double p = 0.0;
        #pragma unroll
        for (int t = 0; t < 8; ++t)
            p = fma((double)a[t], (double)xj[lane * 8 + t], p);
        #pragma unroll
        for (int off = 32; off > 0; off >>= 1)
            p += __shfl_down(p, off);
        if (lane == 0) scand[cc] = p * ir * invn[j];
    }
    __syncthreads();

    if (wave == 0) {
        double v = -1e300;
        int idx = 0x7FFFFFFF;
        if (lane < NC) {
            v = scand[lane];
            idx = cinds[(size_t)row * NC + lane];
        }
        int rank = 0;
        for (int m = 0; m < NC; ++m) {
            const double vm = scand[m];
            const int im = cinds[(size_t)row * NC + m];
            if (vm > v || (vm == v && im < idx)) ++rank;
        }
        float contrib = 0.f;
        if (lane < NC && rank < KK) {
            const float vf = (float)v;
            vals[(size_t)row * KK + rank] = vf;
            inds[(size_t)row * KK + rank] = idx;
            contrib = vf;
        }
        #pragma unroll
        for (int off = 32; off > 0; off >>= 1)
            contrib += __shfl_down(contrib, off);
        if (lane == 0) norm_row[row] = contrib;
    }
}

// ---------------------------------------------------------------------------
// Edge-chain kernels (310k edges each, trivial cost)
// ---------------------------------------------------------------------------
__global__ void scatter_norm_col(const float* __restrict__ vals,
                                 const int* __restrict__ inds,
                                 float* __restrict__ norm_col) {
    const int e = blockIdx.x * 256 + threadIdx.x;
    if (e >= EDGES) return;
    atomicAdd(&norm_col[inds[e]], vals[e]);
}

__global__ void values_and_deg(const float* __restrict__ vals,
                               const int* __restrict__ inds,
                               const float* __restrict__ norm_row,
                               const float* __restrict__ norm_col,
                               float* __restrict__ vrelu,
                               float* __restrict__ deg) {
    const int e = blockIdx.x * 256 + threadIdx.x;
    if (e >= EDGES) return;
    const int i = e / KK;
    const int j = inds[e];
    const float ni = norm_row[i] + norm_col[i];
    const float nj = norm_row[j] + norm_col[j];
    float v = vals[e] * (1.0f / sqrtf(ni)) * (1.0f / sqrtf(nj));
    if (v != v) v = 0.f;           // NaN -> 0
    v = fmaxf(v, 0.f);             // relu (both symmetric copies)
    vrelu[e] = v;
    atomicAdd(&deg[i], v);
    atomicAdd(&deg[j], v);
}

__global__ void compute_dinv(const float* __restrict__ deg, float* __restrict__ dinv) {
    const int i = blockIdx.x * 256 + threadIdx.x;
    if (i >= NN) return;
    float di = 1.0f / sqrtf(deg[i]);
    if (!isfinite(di)) di = 0.f;
    dinv[i] = di;
}

__global__ void scatter_out(const float* __restrict__ vrelu,
                            const int* __restrict__ inds,
                            const float* __restrict__ dinv,
                            float* __restrict__ out) {
    const int e = blockIdx.x * 256 + threadIdx.x;
    if (e >= EDGES) return;
    const int i = e / KK;
    const int j = inds[e];
    const float nv = vrelu[e] * dinv[i] * dinv[j];
    atomicAdd(&out[(size_t)i * NN + j], nv);
    atomicAdd(&out[(size_t)j * NN + i], nv);
}

// ---------------------------------------------------------------------------
// Launch
// ---------------------------------------------------------------------------
extern "C" void kernel_launch(void* const* d_in, const int* in_sizes, int n_in,
                              void* d_out, int out_size, void* d_ws, size_t ws_size,
                              hipStream_t stream) {
    const float* x = (const float*)d_in[0];
    float* out = (float*)d_out;
    float* ws = (float*)d_ws;

    // workspace layout (f32-element offsets), total ~15.8 MB
    unsigned short* xh   = (unsigned short*)ws;               // 5,120,000 u16 -> 2,560,000 slots
    double* invn         = (double*)(ws + 2560000);           // 10,000 f64 (20,000 slots, 8B-aligned)
    int*    cinds        = (int*)(ws + 2580000);              // 400,000
    float*  vals         = ws + 2980000;                      // 310,000
    int*    inds         = (int*)(ws + 3290000);              // 310,000
    float*  norm_row     = ws + 3600000;                      // 10,000
    float*  norm_col     = ws + 3610000;                      // 10,000
    float*  deg          = ws + 3620000;                      // 10,000
    float*  dinv         = ws + 3630000;                      // 10,000
    float*  vrelu        = ws + 3640000;                      // 310,000

    // 1) row normalize -> bf16 + f64 inv norms
    normalize_rows<<<NN, 256, 0, stream>>>(x, xh, invn);

    // 2) sims into d_out (scratch) via bf16 MFMA (1-D grid, XCD-swizzled in-kernel)
    gemm_mfma<<<GDIM * GDIM, 256, 0, stream>>>(xh, out);

    // 3) per-row top-40 candidates (f32)
    topk_rows<<<NN, 256, 0, stream>>>(out, cinds);

    // 4) exact f64 rescore + final top-31 selection
    rescore_topk<<<NN, 256, 0, stream>>>(x, invn, cinds, vals, inds, norm_row);

    // 5) edge normalization chain
    hipMemsetAsync(norm_col, 0, NN * sizeof(float), stream);
    hipMemsetAsync(deg, 0, NN * sizeof(float), stream);
    const int eb = (EDGES + 255) / 256;
    scatter_norm_col<<<eb, 256, 0, stream>>>(vals, inds, norm_col);
    values_and_deg<<<eb, 256, 0, stream>>>(vals, inds, norm_row, norm_col, vrelu, deg);
    compute_dinv<<<(NN + 255) / 256, 256, 0, stream>>>(deg, dinv);

    // 6) zero the dense output, then scatter symmetric normalized edges
    hipMemsetAsync(out, 0, (size_t)NN * NN * sizeof(float), stream);
    scatter_out<<<eb, 256, 0, stream>>>(vrelu, inds, dinv, out);
}

// Round 5
// 663.072 us; speedup vs baseline: 2.8056x; 1.1922x over previous
//
#include <hip/hip_runtime.h>
#include <hip/hip_bf16.h>
#include <math.h>

// Problem constants (reference: N=10000, D=512, k=30 -> k+1=31 neighbors incl. self)
#define NN 10000
#define DD 512
#define KK 31
#define NCTGT 40            // min candidates (threshold target)
#define NCMAX 128           // candidate capacity per row
#define EDGES (NN * KK)     // 310000

typedef __attribute__((ext_vector_type(8))) short short8v;   // 8 bf16 (4 VGPRs)
typedef __attribute__((ext_vector_type(4))) float f32x4;     // MFMA C/D frag

__device__ inline unsigned short f32_to_bf16_rne(float f) {
    unsigned u = __float_as_uint(f);
    u += 0x7FFFu + ((u >> 16) & 1u);   // round-to-nearest-even
    return (unsigned short)(u >> 16);
}

// ---------------------------------------------------------------------------
// Kernel 1: row L2-normalize x; emit bf16(xn) and the f64 inverse norm.
// ---------------------------------------------------------------------------
__global__ __launch_bounds__(256) void normalize_rows(const float* __restrict__ x,
                                                      unsigned short* __restrict__ xh,
                                                      double* __restrict__ invn) {
    const int row = blockIdx.x;
    const int tid = threadIdx.x;
    const float* xr = x + (size_t)row * DD;
    const float v0 = xr[tid];
    const float v1 = xr[tid + 256];
    double ss = (double)v0 * (double)v0 + (double)v1 * (double)v1;
    #pragma unroll
    for (int off = 32; off > 0; off >>= 1) ss += __shfl_down(ss, off);
    __shared__ double wsum[4];
    __shared__ double sinv;
    if ((tid & 63) == 0) wsum[tid >> 6] = ss;
    __syncthreads();
    if (tid == 0) {
        const double iv = 1.0 / sqrt(wsum[0] + wsum[1] + wsum[2] + wsum[3]);
        invn[row] = iv;
        sinv = iv;
    }
    __syncthreads();
    const float nv = (float)sinv;
    xh[(size_t)row * DD + tid]       = f32_to_bf16_rne(v0 * nv);
    xh[(size_t)row * DD + tid + 256] = f32_to_bf16_rne(v1 * nv);
}

// ---------------------------------------------------------------------------
// Kernel 2: sims ~= bf16(xn) * bf16(xn)^T  (MFMA; error ~1e-4, candidate-safe)
// 128x128 tile, BK=64, 4 waves (2x2), XOR-swizzled LDS (0 bank conflicts, R3),
// bijective XCD block swizzle.
// ---------------------------------------------------------------------------
#define TILE 128
#define BKK 64
#define GDIM 79   // ceil(10000/128)

__global__ __launch_bounds__(256) void gemm_mfma(const unsigned short* __restrict__ hi,
                                                 float* __restrict__ out) {
    __shared__ unsigned short lds[2][TILE * BKK];   // A-hi, B-hi: 16KB each

    // bijective XCD swizzle: nwg=6241, q=780, r=1
    const int orig = blockIdx.x;
    const int xcd = orig & 7;
    const int pos = orig >> 3;
    const int nw = (xcd < 1 ? xcd * 781 : 781 + (xcd - 1) * 780) + pos;
    const int bi = nw / GDIM, bj = nw % GDIM;

    const int row0 = bi * TILE, col0 = bj * TILE;
    const int tid = threadIdx.x;
    const int l = tid & 63, wid = tid >> 6;
    const int wm = wid >> 1, wn = wid & 1;       // 2x2 wave grid
    const int c = l & 15, g = l >> 4;            // frag col / k-group

    f32x4 acc[4][4];
    #pragma unroll
    for (int i = 0; i < 4; ++i)
        #pragma unroll
        for (int j = 0; j < 4; ++j) acc[i][j] = (f32x4){0.f, 0.f, 0.f, 0.f};

    for (int k0 = 0; k0 < DD; k0 += BKK) {
        #pragma unroll
        for (int i = 0; i < 4; ++i) {
            const int s = i * 256 + tid;         // slot id
            const int r = s >> 3;                // row in tile (0..127)
            const int cs = s & 7;                // 16B k-chunk (0..7)
            const int ldso = r * BKK + ((cs ^ (r & 7)) * 8);
            const int gar = row0 + r, gbr = col0 + r;
            short8v ah = (short8v)0, bh = (short8v)0;
            const size_t goff = (size_t)(k0 + cs * 8);
            if (gar < NN) ah = *(const short8v*)(hi + (size_t)gar * DD + goff);
            if (gbr < NN) bh = *(const short8v*)(hi + (size_t)gbr * DD + goff);
            *(short8v*)(&lds[0][ldso]) = ah;
            *(short8v*)(&lds[1][ldso]) = bh;
        }
        __syncthreads();

        #pragma unroll
        for (int ks = 0; ks < 2; ++ks) {
            short8v a_hi[4], b_hi[4];
            const int kc = ks * 4 + g;
            #pragma unroll
            for (int fm = 0; fm < 4; ++fm) {
                const int r = wm * 64 + fm * 16 + c;
                a_hi[fm] = *(const short8v*)(&lds[0][r * BKK + ((kc ^ (r & 7)) * 8)]);
            }
            #pragma unroll
            for (int fn = 0; fn < 4; ++fn) {
                const int r = wn * 64 + fn * 16 + c;
                b_hi[fn] = *(const short8v*)(&lds[1][r * BKK + ((kc ^ (r & 7)) * 8)]);
            }
            #pragma unroll
            for (int fm = 0; fm < 4; ++fm)
                #pragma unroll
                for (int fn = 0; fn < 4; ++fn)
                    acc[fm][fn] = __builtin_amdgcn_mfma_f32_16x16x32_bf16(
                        a_hi[fm], b_hi[fn], acc[fm][fn], 0, 0, 0);
        }
        __syncthreads();
    }

    #pragma unroll
    for (int fm = 0; fm < 4; ++fm) {
        #pragma unroll
        for (int fn = 0; fn < 4; ++fn) {
            const int gc = col0 + wn * 64 + fn * 16 + c;
            if (gc >= NN) continue;
            #pragma unroll
            for (int r = 0; r < 4; ++r) {
                const int gr = row0 + wm * 64 + fm * 16 + g * 4 + r;
                if (gr < NN) out[(size_t)gr * NN + gc] = acc[fm][fn][r];
            }
        }
    }
}

// ---------------------------------------------------------------------------
// Kernel 3: radix-select candidates per row.  Pass 1: 13-bit histogram of the
// monotone-mapped float bits.  Suffix-scan finds bucket b* where cumulative
// count (from the top) first reaches NCTGT.  Pass 2: compact all indices with
// value in bucket >= b* (unordered; rescore re-ranks deterministically).
// ---------------------------------------------------------------------------
#define NBKT 8192
#define BSH 19   // 32 - 13

__global__ __launch_bounds__(256) void topk_radix(const float* __restrict__ sims,
                                                  int* __restrict__ cinds,
                                                  int* __restrict__ ccnt) {
    const int row = blockIdx.x;
    const int tid = threadIdx.x;
    const float4* s4 = (const float4*)(sims + (size_t)row * NN);

    __shared__ unsigned hist[NBKT];
    __shared__ unsigned suf[256];
    __shared__ int bstar_sh;
    __shared__ unsigned cnt_sh;

    #pragma unroll
    for (int i = 0; i < NBKT / 256; ++i) hist[tid + i * 256] = 0u;
    if (tid == 0) cnt_sh = 0u;
    __syncthreads();

    // ---- pass 1: histogram (2500 float4 per row) ----
    for (int i = tid; i < NN / 4; i += 256) {
        const float4 v = s4[i];
        const float arr[4] = {v.x, v.y, v.z, v.w};
        #pragma unroll
        for (int e = 0; e < 4; ++e) {
            unsigned u = __float_as_uint(arr[e]);
            unsigned m = (u & 0x80000000u) ? ~u : (u | 0x80000000u);
            atomicAdd(&hist[m >> BSH], 1u);
        }
    }
    __syncthreads();

    // ---- per-thread partial over 32 buckets, then inclusive suffix scan ----
    unsigned ps = 0u;
    #pragma unroll
    for (int i = 0; i < 32; ++i) ps += hist[tid * 32 + i];
    unsigned acc = ps;
    suf[tid] = acc;
    __syncthreads();
    for (int off = 1; off < 256; off <<= 1) {
        const unsigned add = (tid + off < 256) ? suf[tid + off] : 0u;
        __syncthreads();
        acc += add;
        suf[tid] = acc;
        __syncthreads();
    }
    // suf[t] = sum over buckets [t*32, end); exclusive = suf[t] - ps
    const unsigned excl = acc - ps;
    if (excl < NCTGT && acc >= NCTGT) {    // crossing happens inside my chunk
        unsigned run = excl;
        for (int i = 31; i >= 0; --i) {
            run += hist[tid * 32 + i];
            if (run >= NCTGT) { bstar_sh = tid * 32 + i; break; }
        }
    }
    __syncthreads();
    const unsigned mthresh = ((unsigned)bstar_sh) << BSH;

    // ---- pass 2: compact indices with monotone value >= bucket b* floor ----
    for (int i = tid; i < NN / 4; i += 256) {
        const float4 v = s4[i];
        const float arr[4] = {v.x, v.y, v.z, v.w};
        #pragma unroll
        for (int e = 0; e < 4; ++e) {
            unsigned u = __float_as_uint(arr[e]);
            unsigned m = (u & 0x80000000u) ? ~u : (u | 0x80000000u);
            if (m >= mthresh) {
                const unsigned pos = atomicAdd(&cnt_sh, 1u);
                if (pos < NCMAX) cinds[(size_t)row * NCMAX + pos] = i * 4 + e;
            }
        }
    }
    __syncthreads();
    if (tid == 0) ccnt[row] = (int)(cnt_sh < NCMAX ? cnt_sh : NCMAX);
}

// ---------------------------------------------------------------------------
// Kernel 4: f64 rescore of the candidates; exact deterministic re-ranking by
// (value desc, index asc); emits final 31 (vals f32, inds) + norm_row.
// ---------------------------------------------------------------------------
__global__ __launch_bounds__(256) void rescore_topk(const float* __restrict__ x,
                                                    const double* __restrict__ invn,
                                                    const int* __restrict__ cinds,
                                                    const int* __restrict__ ccnt,
                                                    float* __restrict__ vals,
                                                    int* __restrict__ inds,
                                                    float* __restrict__ norm_row) {
    const int row = blockIdx.x;
    const int tid = threadIdx.x;
    const int lane = tid & 63;
    const int wave = tid >> 6;
    const int cnt = ccnt[row];

    __shared__ double scand[NCMAX];
    __shared__ int    scidx[NCMAX];
    __shared__ float  topv[KK];

    if (tid < cnt) scidx[tid] = cinds[(size_t)row * NCMAX + tid];
    __syncthreads();

    const float* xr = x + (size_t)row * DD;
    float a[8];
    #pragma unroll
    for (int t = 0; t < 8; ++t) a[t] = xr[lane * 8 + t];
    const double ir = invn[row];

    for (int cc = wave; cc < cnt; cc += 4) {
        const int j = scidx[cc];
        const float* xj = x + (size_t)j * DD;
        double p = 0.0;
        #pragma unroll
        for (int t = 0; t < 8; ++t)
            p = fma((double)a[t], (double)xj[lane * 8 + t], p);
        #pragma unroll
        for (int off = 32; off > 0; off >>= 1)
            p += __shfl_down(p, off);
        if (lane == 0) scand[cc] = p * ir * invn[j];
    }
    __syncthreads();

    if (tid < cnt) {
        const double v = scand[tid];
        const int idx = scidx[tid];
        int rank = 0;
        for (int m = 0; m < cnt; ++m) {
            const double vm = scand[m];
            const int im = scidx[m];
            if (vm > v || (vm == v && im < idx)) ++rank;
        }
        if (rank < KK) {
            const float vf = (float)v;
            vals[(size_t)row * KK + rank] = vf;
            inds[(size_t)row * KK + rank] = idx;
            topv[rank] = vf;
        }
    }
    __syncthreads();
    if (tid < 64) {
        float contrib = (tid < KK) ? topv[tid] : 0.f;
        #pragma unroll
        for (int off = 32; off > 0; off >>= 1)
            contrib += __shfl_down(contrib, off);
        if (tid == 0) norm_row[row] = contrib;
    }
}

// ---------------------------------------------------------------------------
// Edge-chain kernels (310k edges each, trivial cost)
// ---------------------------------------------------------------------------
__global__ void scatter_norm_col(const float* __restrict__ vals,
                                 const int* __restrict__ inds,
                                 float* __restrict__ norm_col) {
    const int e = blockIdx.x * 256 + threadIdx.x;
    if (e >= EDGES) return;
    atomicAdd(&norm_col[inds[e]], vals[e]);
}

__global__ void values_and_deg(const float* __restrict__ vals,
                               const int* __restrict__ inds,
                               const float* __restrict__ norm_row,
                               const float* __restrict__ norm_col,
                               float* __restrict__ vrelu,
                               float* __restrict__ deg) {
    const int e = blockIdx.x * 256 + threadIdx.x;
    if (e >= EDGES) return;
    const int i = e / KK;
    const int j = inds[e];
    const float ni = norm_row[i] + norm_col[i];
    const float nj = norm_row[j] + norm_col[j];
    float v = vals[e] * (1.0f / sqrtf(ni)) * (1.0f / sqrtf(nj));
    if (v != v) v = 0.f;           // NaN -> 0
    v = fmaxf(v, 0.f);             // relu (both symmetric copies)
    vrelu[e] = v;
    atomicAdd(&deg[i], v);
    atomicAdd(&deg[j], v);
}

__global__ void compute_dinv(const float* __restrict__ deg, float* __restrict__ dinv) {
    const int i = blockIdx.x * 256 + threadIdx.x;
    if (i >= NN) return;
    float di = 1.0f / sqrtf(deg[i]);
    if (!isfinite(di)) di = 0.f;
    dinv[i] = di;
}

__global__ void scatter_out(const float* __restrict__ vrelu,
                            const int* __restrict__ inds,
                            const float* __restrict__ dinv,
                            float* __restrict__ out) {
    const int e = blockIdx.x * 256 + threadIdx.x;
    if (e >= EDGES) return;
    const int i = e / KK;
    const int j = inds[e];
    const float nv = vrelu[e] * dinv[i] * dinv[j];
    atomicAdd(&out[(size_t)i * NN + j], nv);
    atomicAdd(&out[(size_t)j * NN + i], nv);
}

// ---------------------------------------------------------------------------
// Launch
// ---------------------------------------------------------------------------
extern "C" void kernel_launch(void* const* d_in, const int* in_sizes, int n_in,
                              void* d_out, int out_size, void* d_ws, size_t ws_size,
                              hipStream_t stream) {
    const float* x = (const float*)d_in[0];
    float* out = (float*)d_out;
    float* ws = (float*)d_ws;

    // workspace layout (f32-element offsets), total ~19.4 MB
    unsigned short* xh   = (unsigned short*)ws;               // 5,120,000 u16 -> 2,560,000 slots
    double* invn         = (double*)(ws + 2560000);           // 10,000 f64 (20,000 slots, 8B-aligned)
    int*    cinds        = (int*)(ws + 2580000);              // 10,000 x 128 = 1,280,000
    int*    ccnt         = (int*)(ws + 3860000);              // 10,000
    float*  vals         = ws + 3870000;                      // 310,000
    int*    inds         = (int*)(ws + 4180000);              // 310,000
    float*  norm_row     = ws + 4490000;                      // 10,000
    float*  norm_col     = ws + 4500000;                      // 10,000
    float*  deg          = ws + 4510000;                      // 10,000
    float*  dinv         = ws + 4520000;                      // 10,000
    float*  vrelu        = ws + 4530000;                      // 310,000

    // 1) row normalize -> bf16 + f64 inv norms
    normalize_rows<<<NN, 256, 0, stream>>>(x, xh, invn);

    // 2) sims into d_out (scratch) via bf16 MFMA
    gemm_mfma<<<GDIM * GDIM, 256, 0, stream>>>(xh, out);

    // 3) per-row candidate superset via radix-select
    topk_radix<<<NN, 256, 0, stream>>>(out, cinds, ccnt);

    // 4) exact f64 rescore + final top-31 selection
    rescore_topk<<<NN, 256, 0, stream>>>(x, invn, cinds, ccnt, vals, inds, norm_row);

    // 5) edge normalization chain
    hipMemsetAsync(norm_col, 0, NN * sizeof(float), stream);
    hipMemsetAsync(deg, 0, NN * sizeof(float), stream);
    const int eb = (EDGES + 255) / 256;
    scatter_norm_col<<<eb, 256, 0, stream>>>(vals, inds, norm_col);
    values_and_deg<<<eb, 256, 0, stream>>>(vals, inds, norm_row, norm_col, vrelu, deg);
    compute_dinv<<<(NN + 255) / 256, 256, 0, stream>>>(deg, dinv);

    // 6) zero the dense output, then scatter symmetric normalized edges
    hipMemsetAsync(out, 0, (size_t)NN * NN * sizeof(float), stream);
    scatter_out<<<eb, 256, 0, stream>>>(vrelu, inds, dinv, out);
}

// Round 6
// 645.101 us; speedup vs baseline: 2.8838x; 1.0279x over previous
//
#include <hip/hip_runtime.h>
#include <hip/hip_bf16.h>
#include <math.h>

// Problem constants (reference: N=10000, D=512, k=30 -> k+1=31 neighbors incl. self)
#define NN 10000
#define DD 512
#define KK 31
#define NCTGT 40            // min candidates (threshold target)
#define NCMAX 128           // candidate capacity per row
#define EDGES (NN * KK)     // 310000

typedef __attribute__((ext_vector_type(8))) short short8v;   // 8 bf16 (4 VGPRs)
typedef __attribute__((ext_vector_type(4))) float f32x4;     // MFMA C/D frag

__device__ inline unsigned short f32_to_bf16_rne(float f) {
    unsigned u = __float_as_uint(f);
    u += 0x7FFFu + ((u >> 16) & 1u);   // round-to-nearest-even
    return (unsigned short)(u >> 16);
}

// ---------------------------------------------------------------------------
// Kernel 1: row L2-normalize x; emit bf16(xn) and the f64 inverse norm.
// ---------------------------------------------------------------------------
__global__ __launch_bounds__(256) void normalize_rows(const float* __restrict__ x,
                                                      unsigned short* __restrict__ xh,
                                                      double* __restrict__ invn) {
    const int row = blockIdx.x;
    const int tid = threadIdx.x;
    const float* xr = x + (size_t)row * DD;
    const float v0 = xr[tid];
    const float v1 = xr[tid + 256];
    double ss = (double)v0 * (double)v0 + (double)v1 * (double)v1;
    #pragma unroll
    for (int off = 32; off > 0; off >>= 1) ss += __shfl_down(ss, off);
    __shared__ double wsum[4];
    __shared__ double sinv;
    if ((tid & 63) == 0) wsum[tid >> 6] = ss;
    __syncthreads();
    if (tid == 0) {
        const double iv = 1.0 / sqrt(wsum[0] + wsum[1] + wsum[2] + wsum[3]);
        invn[row] = iv;
        sinv = iv;
    }
    __syncthreads();
    const float nv = (float)sinv;
    xh[(size_t)row * DD + tid]       = f32_to_bf16_rne(v0 * nv);
    xh[(size_t)row * DD + tid + 256] = f32_to_bf16_rne(v1 * nv);
}

// ---------------------------------------------------------------------------
// Kernel 2: sims ~= bf16(xn) * bf16(xn)^T  (MFMA; error ~1e-4, candidate-safe)
// 128x128 tile, BK=64, 4 waves (2x2), XOR-swizzled LDS (0 bank conflicts, R3),
// bijective XCD block swizzle.
// ---------------------------------------------------------------------------
#define TILE 128
#define BKK 64
#define GDIM 79   // ceil(10000/128)

__global__ __launch_bounds__(256) void gemm_mfma(const unsigned short* __restrict__ hi,
                                                 float* __restrict__ out) {
    __shared__ unsigned short lds[2][TILE * BKK];   // A-hi, B-hi: 16KB each

    // bijective XCD swizzle: nwg=6241, q=780, r=1
    const int orig = blockIdx.x;
    const int xcd = orig & 7;
    const int pos = orig >> 3;
    const int nw = (xcd < 1 ? xcd * 781 : 781 + (xcd - 1) * 780) + pos;
    const int bi = nw / GDIM, bj = nw % GDIM;

    const int row0 = bi * TILE, col0 = bj * TILE;
    const int tid = threadIdx.x;
    const int l = tid & 63, wid = tid >> 6;
    const int wm = wid >> 1, wn = wid & 1;       // 2x2 wave grid
    const int c = l & 15, g = l >> 4;            // frag col / k-group

    f32x4 acc[4][4];
    #pragma unroll
    for (int i = 0; i < 4; ++i)
        #pragma unroll
        for (int j = 0; j < 4; ++j) acc[i][j] = (f32x4){0.f, 0.f, 0.f, 0.f};

    for (int k0 = 0; k0 < DD; k0 += BKK) {
        #pragma unroll
        for (int i = 0; i < 4; ++i) {
            const int s = i * 256 + tid;         // slot id
            const int r = s >> 3;                // row in tile (0..127)
            const int cs = s & 7;                // 16B k-chunk (0..7)
            const int ldso = r * BKK + ((cs ^ (r & 7)) * 8);
            const int gar = row0 + r, gbr = col0 + r;
            short8v ah = (short8v)0, bh = (short8v)0;
            const size_t goff = (size_t)(k0 + cs * 8);
            if (gar < NN) ah = *(const short8v*)(hi + (size_t)gar * DD + goff);
            if (gbr < NN) bh = *(const short8v*)(hi + (size_t)gbr * DD + goff);
            *(short8v*)(&lds[0][ldso]) = ah;
            *(short8v*)(&lds[1][ldso]) = bh;
        }
        __syncthreads();

        #pragma unroll
        for (int ks = 0; ks < 2; ++ks) {
            short8v a_hi[4], b_hi[4];
            const int kc = ks * 4 + g;
            #pragma unroll
            for (int fm = 0; fm < 4; ++fm) {
                const int r = wm * 64 + fm * 16 + c;
                a_hi[fm] = *(const short8v*)(&lds[0][r * BKK + ((kc ^ (r & 7)) * 8)]);
            }
            #pragma unroll
            for (int fn = 0; fn < 4; ++fn) {
                const int r = wn * 64 + fn * 16 + c;
                b_hi[fn] = *(const short8v*)(&lds[1][r * BKK + ((kc ^ (r & 7)) * 8)]);
            }
            #pragma unroll
            for (int fm = 0; fm < 4; ++fm)
                #pragma unroll
                for (int fn = 0; fn < 4; ++fn)
                    acc[fm][fn] = __builtin_amdgcn_mfma_f32_16x16x32_bf16(
                        a_hi[fm], b_hi[fn], acc[fm][fn], 0, 0, 0);
        }
        __syncthreads();
    }

    #pragma unroll
    for (int fm = 0; fm < 4; ++fm) {
        #pragma unroll
        for (int fn = 0; fn < 4; ++fn) {
            const int gc = col0 + wn * 64 + fn * 16 + c;
            if (gc >= NN) continue;
            #pragma unroll
            for (int r = 0; r < 4; ++r) {
                const int gr = row0 + wm * 64 + fm * 16 + g * 4 + r;
                if (gr < NN) out[(size_t)gr * NN + gc] = acc[fm][fn][r];
            }
        }
    }
}

// ---------------------------------------------------------------------------
// Kernel 3: radix-select candidates per row + FUSED output zeroing.
// Pass 1: 13-bit histogram of monotone-mapped float bits.  Suffix-scan finds
// bucket b* where cumulative count (from top) first reaches NCTGT.
// Pass 2: compact indices with value >= bucket b* floor AND store zeros back
// over the row (each block owns its row exclusively; replaces the 400 MB
// memset that cost ~240 us as a separate rocclr fill dispatch).
// ---------------------------------------------------------------------------
#define NBKT 8192
#define BSH 19   // 32 - 13

__global__ __launch_bounds__(256) void topk_radix(float* __restrict__ sims,
                                                  int* __restrict__ cinds,
                                                  int* __restrict__ ccnt) {
    const int row = blockIdx.x;
    const int tid = threadIdx.x;
    float4* s4 = (float4*)(sims + (size_t)row * NN);

    __shared__ unsigned hist[NBKT];
    __shared__ unsigned suf[256];
    __shared__ int bstar_sh;
    __shared__ unsigned cnt_sh;

    #pragma unroll
    for (int i = 0; i < NBKT / 256; ++i) hist[tid + i * 256] = 0u;
    if (tid == 0) cnt_sh = 0u;
    __syncthreads();

    // ---- pass 1: histogram (2500 float4 per row) ----
    for (int i = tid; i < NN / 4; i += 256) {
        const float4 v = s4[i];
        const float arr[4] = {v.x, v.y, v.z, v.w};
        #pragma unroll
        for (int e = 0; e < 4; ++e) {
            unsigned u = __float_as_uint(arr[e]);
            unsigned m = (u & 0x80000000u) ? ~u : (u | 0x80000000u);
            atomicAdd(&hist[m >> BSH], 1u);
        }
    }
    __syncthreads();

    // ---- per-thread partial over 32 buckets, then inclusive suffix scan ----
    unsigned ps = 0u;
    #pragma unroll
    for (int i = 0; i < 32; ++i) ps += hist[tid * 32 + i];
    unsigned acc = ps;
    suf[tid] = acc;
    __syncthreads();
    for (int off = 1; off < 256; off <<= 1) {
        const unsigned add = (tid + off < 256) ? suf[tid + off] : 0u;
        __syncthreads();
        acc += add;
        suf[tid] = acc;
        __syncthreads();
    }
    // suf[t] = sum over buckets [t*32, end); exclusive = suf[t] - ps
    const unsigned excl = acc - ps;
    if (excl < NCTGT && acc >= NCTGT) {    // crossing happens inside my chunk
        unsigned run = excl;
        for (int i = 31; i >= 0; --i) {
            run += hist[tid * 32 + i];
            if (run >= NCTGT) { bstar_sh = tid * 32 + i; break; }
        }
    }
    __syncthreads();
    const unsigned mthresh = ((unsigned)bstar_sh) << BSH;
    const float4 zero4 = make_float4(0.f, 0.f, 0.f, 0.f);

    // ---- pass 2: compact indices >= threshold, then zero the row in place ----
    for (int i = tid; i < NN / 4; i += 256) {
        const float4 v = s4[i];
        const float arr[4] = {v.x, v.y, v.z, v.w};
        #pragma unroll
        for (int e = 0; e < 4; ++e) {
            unsigned u = __float_as_uint(arr[e]);
            unsigned m = (u & 0x80000000u) ? ~u : (u | 0x80000000u);
            if (m >= mthresh) {
                const unsigned pos = atomicAdd(&cnt_sh, 1u);
                if (pos < NCMAX) cinds[(size_t)row * NCMAX + pos] = i * 4 + e;
            }
        }
        s4[i] = zero4;   // fused zero-fill (row-exclusive, race-free)
    }
    __syncthreads();
    if (tid == 0) ccnt[row] = (int)(cnt_sh < NCMAX ? cnt_sh : NCMAX);
}

// ---------------------------------------------------------------------------
// Kernel 4: f64 rescore of the candidates; exact deterministic re-ranking by
// (value desc, index asc); emits final 31 (vals f32, inds) + norm_row.
// ---------------------------------------------------------------------------
__global__ __launch_bounds__(256) void rescore_topk(const float* __restrict__ x,
                                                    const double* __restrict__ invn,
                                                    const int* __restrict__ cinds,
                                                    const int* __restrict__ ccnt,
                                                    float* __restrict__ vals,
                                                    int* __restrict__ inds,
                                                    float* __restrict__ norm_row) {
    const int row = blockIdx.x;
    const int tid = threadIdx.x;
    const int lane = tid & 63;
    const int wave = tid >> 6;
    const int cnt = ccnt[row];

    __shared__ double scand[NCMAX];
    __shared__ int    scidx[NCMAX];
    __shared__ float  topv[KK];

    if (tid < cnt) scidx[tid] = cinds[(size_t)row * NCMAX + tid];
    __syncthreads();

    const float* xr = x + (size_t)row * DD;
    float a[8];
    #pragma unroll
    for (int t = 0; t < 8; ++t) a[t] = xr[lane * 8 + t];
    const double ir = invn[row];

    for (int cc = wave; cc < cnt; cc += 4) {
        const int j = scidx[cc];
        const float* xj = x + (size_t)j * DD;
        double p = 0.0;
        #pragma unroll
        for (int t = 0; t < 8; ++t)
            p = fma((double)a[t], (double)xj[lane * 8 + t], p);
        #pragma unroll
        for (int off = 32; off > 0; off >>= 1)
            p += __shfl_down(p, off);
        if (lane == 0) scand[cc] = p * ir * invn[j];
    }
    __syncthreads();

    if (tid < cnt) {
        const double v = scand[tid];
        const int idx = scidx[tid];
        int rank = 0;
        for (int m = 0; m < cnt; ++m) {
            const double vm = scand[m];
            const int im = scidx[m];
            if (vm > v || (vm == v && im < idx)) ++rank;
        }
        if (rank < KK) {
            const float vf = (float)v;
            vals[(size_t)row * KK + rank] = vf;
            inds[(size_t)row * KK + rank] = idx;
            topv[rank] = vf;
        }
    }
    __syncthreads();
    if (tid < 64) {
        float contrib = (tid < KK) ? topv[tid] : 0.f;
        #pragma unroll
        for (int off = 32; off > 0; off >>= 1)
            contrib += __shfl_down(contrib, off);
        if (tid == 0) norm_row[row] = contrib;
    }
}

// ---------------------------------------------------------------------------
// Edge-chain kernels (310k edges each, trivial cost)
// ---------------------------------------------------------------------------
__global__ void scatter_norm_col(const float* __restrict__ vals,
                                 const int* __restrict__ inds,
                                 float* __restrict__ norm_col) {
    const int e = blockIdx.x * 256 + threadIdx.x;
    if (e >= EDGES) return;
    atomicAdd(&norm_col[inds[e]], vals[e]);
}

__global__ void values_and_deg(const float* __restrict__ vals,
                               const int* __restrict__ inds,
                               const float* __restrict__ norm_row,
                               const float* __restrict__ norm_col,
                               float* __restrict__ vrelu,
                               float* __restrict__ deg) {
    const int e = blockIdx.x * 256 + threadIdx.x;
    if (e >= EDGES) return;
    const int i = e / KK;
    const int j = inds[e];
    const float ni = norm_row[i] + norm_col[i];
    const float nj = norm_row[j] + norm_col[j];
    float v = vals[e] * (1.0f / sqrtf(ni)) * (1.0f / sqrtf(nj));
    if (v != v) v = 0.f;           // NaN -> 0
    v = fmaxf(v, 0.f);             // relu (both symmetric copies)
    vrelu[e] = v;
    atomicAdd(&deg[i], v);
    atomicAdd(&deg[j], v);
}

__global__ void compute_dinv(const float* __restrict__ deg, float* __restrict__ dinv) {
    const int i = blockIdx.x * 256 + threadIdx.x;
    if (i >= NN) return;
    float di = 1.0f / sqrtf(deg[i]);
    if (!isfinite(di)) di = 0.f;
    dinv[i] = di;
}

__global__ void scatter_out(const float* __restrict__ vrelu,
                            const int* __restrict__ inds,
                            const float* __restrict__ dinv,
                            float* __restrict__ out) {
    const int e = blockIdx.x * 256 + threadIdx.x;
    if (e >= EDGES) return;
    const int i = e / KK;
    const int j = inds[e];
    const float nv = vrelu[e] * dinv[i] * dinv[j];
    atomicAdd(&out[(size_t)i * NN + j], nv);
    atomicAdd(&out[(size_t)j * NN + i], nv);
}

// ---------------------------------------------------------------------------
// Launch
// ---------------------------------------------------------------------------
extern "C" void kernel_launch(void* const* d_in, const int* in_sizes, int n_in,
                              void* d_out, int out_size, void* d_ws, size_t ws_size,
                              hipStream_t stream) {
    const float* x = (const float*)d_in[0];
    float* out = (float*)d_out;
    float* ws = (float*)d_ws;

    // workspace layout (f32-element offsets), total ~19.4 MB
    unsigned short* xh   = (unsigned short*)ws;               // 5,120,000 u16 -> 2,560,000 slots
    double* invn         = (double*)(ws + 2560000);           // 10,000 f64 (20,000 slots, 8B-aligned)
    int*    cinds        = (int*)(ws + 2580000);              // 10,000 x 128 = 1,280,000
    int*    ccnt         = (int*)(ws + 3860000);              // 10,000
    float*  vals         = ws + 3870000;                      // 310,000
    int*    inds         = (int*)(ws + 4180000);              // 310,000
    float*  norm_row     = ws + 4490000;                      // 10,000
    float*  norm_col     = ws + 4500000;                      // 10,000
    float*  deg          = ws + 4510000;                      // 10,000
    float*  dinv         = ws + 4520000;                      // 10,000
    float*  vrelu        = ws + 4530000;                      // 310,000

    // 1) row normalize -> bf16 + f64 inv norms
    normalize_rows<<<NN, 256, 0, stream>>>(x, xh, invn);

    // 2) sims into d_out (scratch) via bf16 MFMA
    gemm_mfma<<<GDIM * GDIM, 256, 0, stream>>>(xh, out);

    // 3) per-row candidate superset via radix-select + fused zeroing of d_out
    topk_radix<<<NN, 256, 0, stream>>>(out, cinds, ccnt);

    // 4) exact f64 rescore + final top-31 selection
    rescore_topk<<<NN, 256, 0, stream>>>(x, invn, cinds, ccnt, vals, inds, norm_row);

    // 5) edge normalization chain
    hipMemsetAsync(norm_col, 0, NN * sizeof(float), stream);
    hipMemsetAsync(deg, 0, NN * sizeof(float), stream);
    const int eb = (EDGES + 255) / 256;
    scatter_norm_col<<<eb, 256, 0, stream>>>(vals, inds, norm_col);
    values_and_deg<<<eb, 256, 0, stream>>>(vals, inds, norm_row, norm_col, vrelu, deg);
    compute_dinv<<<(NN + 255) / 256, 256, 0, stream>>>(deg, dinv);

    // 6) scatter symmetric normalized edges into the (already zeroed) output
    scatter_out<<<eb, 256, 0, stream>>>(vrelu, inds, dinv, out);
}

// Round 7
// 638.019 us; speedup vs baseline: 2.9158x; 1.0111x over previous
//
#include <hip/hip_runtime.h>
#include <hip/hip_bf16.h>
#include <math.h>

// Problem constants (reference: N=10000, D=512, k=30 -> k+1=31 neighbors incl. self)
#define NN 10000
#define DD 512
#define KK 31
#define NCTGT 48            // min candidates (threshold target; margin vs bf16 noise+quant)
#define NCMAX 128           // candidate capacity per row
#define EDGES (NN * KK)     // 310000

typedef __attribute__((ext_vector_type(8))) short short8v;   // 8 bf16 (4 VGPRs)
typedef __attribute__((ext_vector_type(4))) float f32x4;     // MFMA C/D frag

__device__ inline unsigned short f32_to_bf16_rne(float f) {
    unsigned u = __float_as_uint(f);
    u += 0x7FFFu + ((u >> 16) & 1u);   // round-to-nearest-even
    return (unsigned short)(u >> 16);
}

// monotone order-preserving map of bf16 bit pattern (u16) -> u16
__device__ inline unsigned mono16(unsigned u) {
    return (u & 0x8000u) ? (0xFFFFu & ~u) : (u | 0x8000u);
}

// ---------------------------------------------------------------------------
// Kernel 1: row L2-normalize x; emit bf16(xn) and the f64 inverse norm.
// ---------------------------------------------------------------------------
__global__ __launch_bounds__(256) void normalize_rows(const float* __restrict__ x,
                                                      unsigned short* __restrict__ xh,
                                                      double* __restrict__ invn) {
    const int row = blockIdx.x;
    const int tid = threadIdx.x;
    const float* xr = x + (size_t)row * DD;
    const float v0 = xr[tid];
    const float v1 = xr[tid + 256];
    double ss = (double)v0 * (double)v0 + (double)v1 * (double)v1;
    #pragma unroll
    for (int off = 32; off > 0; off >>= 1) ss += __shfl_down(ss, off);
    __shared__ double wsum[4];
    __shared__ double sinv;
    if ((tid & 63) == 0) wsum[tid >> 6] = ss;
    __syncthreads();
    if (tid == 0) {
        const double iv = 1.0 / sqrt(wsum[0] + wsum[1] + wsum[2] + wsum[3]);
        invn[row] = iv;
        sinv = iv;
    }
    __syncthreads();
    const float nv = (float)sinv;
    xh[(size_t)row * DD + tid]       = f32_to_bf16_rne(v0 * nv);
    xh[(size_t)row * DD + tid + 256] = f32_to_bf16_rne(v1 * nv);
}

// ---------------------------------------------------------------------------
// Kernel 2: simsb(bf16) ~= bf16(xn) * bf16(xn)^T   (MFMA, output quantized to
// bf16 — selection-only precision; the f64 rescore fixes the final set).
// 128x128 tile, BK=64, 4 waves (2x2), XOR-swizzled LDS (0 bank conflicts, R3),
// bijective XCD block swizzle.
// ---------------------------------------------------------------------------
#define TILE 128
#define BKK 64
#define GDIM 79   // ceil(10000/128)

__global__ __launch_bounds__(256) void gemm_mfma(const unsigned short* __restrict__ hi,
                                                 unsigned short* __restrict__ outb) {
    __shared__ unsigned short lds[2][TILE * BKK];   // A-hi, B-hi: 16KB each

    // bijective XCD swizzle: nwg=6241, q=780, r=1
    const int orig = blockIdx.x;
    const int xcd = orig & 7;
    const int pos = orig >> 3;
    const int nw = (xcd < 1 ? xcd * 781 : 781 + (xcd - 1) * 780) + pos;
    const int bi = nw / GDIM, bj = nw % GDIM;

    const int row0 = bi * TILE, col0 = bj * TILE;
    const int tid = threadIdx.x;
    const int l = tid & 63, wid = tid >> 6;
    const int wm = wid >> 1, wn = wid & 1;       // 2x2 wave grid
    const int c = l & 15, g = l >> 4;            // frag col / k-group

    f32x4 acc[4][4];
    #pragma unroll
    for (int i = 0; i < 4; ++i)
        #pragma unroll
        for (int j = 0; j < 4; ++j) acc[i][j] = (f32x4){0.f, 0.f, 0.f, 0.f};

    for (int k0 = 0; k0 < DD; k0 += BKK) {
        #pragma unroll
        for (int i = 0; i < 4; ++i) {
            const int s = i * 256 + tid;         // slot id
            const int r = s >> 3;                // row in tile (0..127)
            const int cs = s & 7;                // 16B k-chunk (0..7)
            const int ldso = r * BKK + ((cs ^ (r & 7)) * 8);
            const int gar = row0 + r, gbr = col0 + r;
            short8v ah = (short8v)0, bh = (short8v)0;
            const size_t goff = (size_t)(k0 + cs * 8);
            if (gar < NN) ah = *(const short8v*)(hi + (size_t)gar * DD + goff);
            if (gbr < NN) bh = *(const short8v*)(hi + (size_t)gbr * DD + goff);
            *(short8v*)(&lds[0][ldso]) = ah;
            *(short8v*)(&lds[1][ldso]) = bh;
        }
        __syncthreads();

        #pragma unroll
        for (int ks = 0; ks < 2; ++ks) {
            short8v a_hi[4], b_hi[4];
            const int kc = ks * 4 + g;
            #pragma unroll
            for (int fm = 0; fm < 4; ++fm) {
                const int r = wm * 64 + fm * 16 + c;
                a_hi[fm] = *(const short8v*)(&lds[0][r * BKK + ((kc ^ (r & 7)) * 8)]);
            }
            #pragma unroll
            for (int fn = 0; fn < 4; ++fn) {
                const int r = wn * 64 + fn * 16 + c;
                b_hi[fn] = *(const short8v*)(&lds[1][r * BKK + ((kc ^ (r & 7)) * 8)]);
            }
            #pragma unroll
            for (int fm = 0; fm < 4; ++fm)
                #pragma unroll
                for (int fn = 0; fn < 4; ++fn)
                    acc[fm][fn] = __builtin_amdgcn_mfma_f32_16x16x32_bf16(
                        a_hi[fm], b_hi[fn], acc[fm][fn], 0, 0, 0);
        }
        __syncthreads();
    }

    // ---- epilogue: bf16 store.  C layout col = l&15, row = (l>>4)*4 + reg.
    #pragma unroll
    for (int fm = 0; fm < 4; ++fm) {
        #pragma unroll
        for (int fn = 0; fn < 4; ++fn) {
            const int gc = col0 + wn * 64 + fn * 16 + c;
            if (gc >= NN) continue;
            #pragma unroll
            for (int r = 0; r < 4; ++r) {
                const int gr = row0 + wm * 64 + fm * 16 + g * 4 + r;
                if (gr < NN) outb[(size_t)gr * NN + gc] = f32_to_bf16_rne(acc[fm][fn][r]);
            }
        }
    }
}

// ---------------------------------------------------------------------------
// Kernel 3: single-pass radix-select per row from bf16 sims (row cached in
// LDS) + fused f32 zero-fill of the output row.
//   - load row (20 KB) into LDS while building a 12-bit histogram of the
//     monotone-mapped bf16 bits
//   - suffix-scan to find bucket b* where cumulative count (from the top)
//     first reaches NCTGT
//   - compact indices with mono16 >= bucket floor (from LDS)
//   - write f32 zeros over d_out row (each block owns its row exclusively)
// ---------------------------------------------------------------------------
#define NBKT 4096
#define BSH16 4   // 16 - 12

__global__ __launch_bounds__(256) void topk_radix(const unsigned short* __restrict__ simsb,
                                                  float* __restrict__ out,
                                                  int* __restrict__ cinds,
                                                  int* __restrict__ ccnt) {
    const int row = blockIdx.x;
    const int tid = threadIdx.x;

    __shared__ unsigned short rowv[NN];        // 20000 B
    __shared__ unsigned hist[NBKT];            // 16384 B
    __shared__ unsigned suf[256];
    __shared__ int bstar_sh;
    __shared__ unsigned cnt_sh;

    #pragma unroll
    for (int i = 0; i < NBKT / 256; ++i) hist[tid + i * 256] = 0u;
    if (tid == 0) cnt_sh = 0u;
    __syncthreads();

    // ---- load row to LDS + histogram (1250 uint4 = 10000 bf16) ----
    const uint4* s4 = (const uint4*)(simsb + (size_t)row * NN);
    for (int i = tid; i < NN / 8; i += 256) {
        const uint4 v = s4[i];
        ((uint4*)rowv)[i] = v;
        const unsigned w[4] = {v.x, v.y, v.z, v.w};
        #pragma unroll
        for (int e = 0; e < 4; ++e) {
            atomicAdd(&hist[mono16(w[e] & 0xFFFFu) >> BSH16], 1u);
            atomicAdd(&hist[mono16(w[e] >> 16) >> BSH16], 1u);
        }
    }
    __syncthreads();

    // ---- per-thread partial over 16 buckets, then inclusive suffix scan ----
    unsigned ps = 0u;
    #pragma unroll
    for (int i = 0; i < 16; ++i) ps += hist[tid * 16 + i];
    unsigned acc = ps;
    suf[tid] = acc;
    __syncthreads();
    for (int off = 1; off < 256; off <<= 1) {
        const unsigned add = (tid + off < 256) ? suf[tid + off] : 0u;
        __syncthreads();
        acc += add;
        suf[tid] = acc;
        __syncthreads();
    }
    const unsigned excl = acc - ps;            // sum over buckets above my chunk
    if (excl < NCTGT && acc >= NCTGT) {        // crossing happens inside my chunk
        unsigned run = excl;
        for (int i = 15; i >= 0; --i) {
            run += hist[tid * 16 + i];
            if (run >= NCTGT) { bstar_sh = tid * 16 + i; break; }
        }
    }
    __syncthreads();
    const unsigned mthresh = ((unsigned)bstar_sh) << BSH16;

    // ---- compact from LDS ----
    for (int i = tid; i < NN / 8; i += 256) {
        const uint4 v = ((const uint4*)rowv)[i];
        const unsigned w[4] = {v.x, v.y, v.z, v.w};
        #pragma unroll
        for (int e = 0; e < 4; ++e) {
            if (mono16(w[e] & 0xFFFFu) >= mthresh) {
                const unsigned pos = atomicAdd(&cnt_sh, 1u);
                if (pos < NCMAX) cinds[(size_t)row * NCMAX + pos] = i * 8 + e * 2;
            }
            if (mono16(w[e] >> 16) >= mthresh) {
                const unsigned pos = atomicAdd(&cnt_sh, 1u);
                if (pos < NCMAX) cinds[(size_t)row * NCMAX + pos] = i * 8 + e * 2 + 1;
            }
        }
    }

    // ---- fused zero-fill of the f32 output row (row-exclusive, race-free) ----
    float4* o4 = (float4*)(out + (size_t)row * NN);
    const float4 zero4 = make_float4(0.f, 0.f, 0.f, 0.f);
    for (int i = tid; i < NN / 4; i += 256) o4[i] = zero4;

    __syncthreads();
    if (tid == 0) ccnt[row] = (int)(cnt_sh < NCMAX ? cnt_sh : NCMAX);
}

// ---------------------------------------------------------------------------
// Kernel 4: f64 rescore of the candidates; exact deterministic re-ranking by
// (value desc, index asc); emits final 31 (vals f32, inds) + norm_row.
// ---------------------------------------------------------------------------
__global__ __launch_bounds__(256) void rescore_topk(const float* __restrict__ x,
                                                    const double* __restrict__ invn,
                                                    const int* __restrict__ cinds,
                                                    const int* __restrict__ ccnt,
                                                    float* __restrict__ vals,
                                                    int* __restrict__ inds,
                                                    float* __restrict__ norm_row) {
    const int row = blockIdx.x;
    const int tid = threadIdx.x;
    const int lane = tid & 63;
    const int wave = tid >> 6;
    const int cnt = ccnt[row];

    __shared__ double scand[NCMAX];
    __shared__ int    scidx[NCMAX];
    __shared__ float  topv[KK];

    if (tid < cnt) scidx[tid] = cinds[(size_t)row * NCMAX + tid];
    __syncthreads();

    const float* xr = x + (size_t)row * DD;
    float a[8];
    #pragma unroll
    for (int t = 0; t < 8; ++t) a[t] = xr[lane * 8 + t];
    const double ir = invn[row];

    for (int cc = wave; cc < cnt; cc += 4) {
        const int j = scidx[cc];
        const float* xj = x + (size_t)j * DD;
        double p = 0.0;
        #pragma unroll
        for (int t = 0; t < 8; ++t)
            p = fma((double)a[t], (double)xj[lane * 8 + t], p);
        #pragma unroll
        for (int off = 32; off > 0; off >>= 1)
            p += __shfl_down(p, off);
        if (lane == 0) scand[cc] = p * ir * invn[j];
    }
    __syncthreads();

    if (tid < cnt) {
        const double v = scand[tid];
        const int idx = scidx[tid];
        int rank = 0;
        for (int m = 0; m < cnt; ++m) {
            const double vm = scand[m];
            const int im = scidx[m];
            if (vm > v || (vm == v && im < idx)) ++rank;
        }
        if (rank < KK) {
            const float vf = (float)v;
            vals[(size_t)row * KK + rank] = vf;
            inds[(size_t)row * KK + rank] = idx;
            topv[rank] = vf;
        }
    }
    __syncthreads();
    if (tid < 64) {
        float contrib = (tid < KK) ? topv[tid] : 0.f;
        #pragma unroll
        for (int off = 32; off > 0; off >>= 1)
            contrib += __shfl_down(contrib, off);
        if (tid == 0) norm_row[row] = contrib;
    }
}

// ---------------------------------------------------------------------------
// Edge-chain kernels (310k edges each, trivial cost)
// ---------------------------------------------------------------------------
__global__ void scatter_norm_col(const float* __restrict__ vals,
                                 const int* __restrict__ inds,
                                 float* __restrict__ norm_col) {
    const int e = blockIdx.x * 256 + threadIdx.x;
    if (e >= EDGES) return;
    atomicAdd(&norm_col[inds[e]], vals[e]);
}

__global__ void values_and_deg(const float* __restrict__ vals,
                               const int* __restrict__ inds,
                               const float* __restrict__ norm_row,
                               const float* __restrict__ norm_col,
                               float* __restrict__ vrelu,
                               float* __restrict__ deg) {
    const int e = blockIdx.x * 256 + threadIdx.x;
    if (e >= EDGES) return;
    const int i = e / KK;
    const int j = inds[e];
    const float ni = norm_row[i] + norm_col[i];
    const float nj = norm_row[j] + norm_col[j];
    float v = vals[e] * (1.0f / sqrtf(ni)) * (1.0f / sqrtf(nj));
    if (v != v) v = 0.f;           // NaN -> 0
    v = fmaxf(v, 0.f);             // relu (both symmetric copies)
    vrelu[e] = v;
    atomicAdd(&deg[i], v);
    atomicAdd(&deg[j], v);
}

__global__ void compute_dinv(const float* __restrict__ deg, float* __restrict__ dinv) {
    const int i = blockIdx.x * 256 + threadIdx.x;
    if (i >= NN) return;
    float di = 1.0f / sqrtf(deg[i]);
    if (!isfinite(di)) di = 0.f;
    dinv[i] = di;
}

__global__ void scatter_out(const float* __restrict__ vrelu,
                            const int* __restrict__ inds,
                            const float* __restrict__ dinv,
                            float* __restrict__ out) {
    const int e = blockIdx.x * 256 + threadIdx.x;
    if (e >= EDGES) return;
    const int i = e / KK;
    const int j = inds[e];
    const float nv = vrelu[e] * dinv[i] * dinv[j];
    atomicAdd(&out[(size_t)i * NN + j], nv);
    atomicAdd(&out[(size_t)j * NN + i], nv);
}

// ---------------------------------------------------------------------------
// Launch
// ---------------------------------------------------------------------------
extern "C" void kernel_launch(void* const* d_in, const int* in_sizes, int n_in,
                              void* d_out, int out_size, void* d_ws, size_t ws_size,
                              hipStream_t stream) {
    const float* x = (const float*)d_in[0];
    float* out = (float*)d_out;
    float* ws = (float*)d_ws;

    // workspace layout (f32-element offsets), total ~219.4 MB (ws_size ~1.6 GB)
    unsigned short* simsb = (unsigned short*)ws;              // 100,000,000 u16 -> 50,000,000 slots
    unsigned short* xh    = (unsigned short*)(ws + 50000000); // 5,120,000 u16 -> 2,560,000 slots
    double* invn          = (double*)(ws + 52560000);         // 10,000 f64 (20,000 slots, 8B-aligned)
    int*    cinds         = (int*)(ws + 52580000);            // 10,000 x 128 = 1,280,000
    int*    ccnt          = (int*)(ws + 53860000);            // 10,000
    float*  vals          = ws + 53870000;                    // 310,000
    int*    inds          = (int*)(ws + 54180000);            // 310,000
    float*  norm_row      = ws + 54490000;                    // 10,000
    float*  norm_col      = ws + 54500000;                    // 10,000
    float*  deg           = ws + 54510000;                    // 10,000
    float*  dinv          = ws + 54520000;                    // 10,000
    float*  vrelu         = ws + 54530000;                    // 310,000

    // 1) row normalize -> bf16 + f64 inv norms
    normalize_rows<<<NN, 256, 0, stream>>>(x, xh, invn);

    // 2) bf16 sims into workspace via bf16 MFMA
    gemm_mfma<<<GDIM * GDIM, 256, 0, stream>>>(xh, simsb);

    // 3) per-row candidate superset via single-pass radix-select + zero d_out
    topk_radix<<<NN, 256, 0, stream>>>(simsb, out, cinds, ccnt);

    // 4) exact f64 rescore + final top-31 selection
    rescore_topk<<<NN, 256, 0, stream>>>(x, invn, cinds, ccnt, vals, inds, norm_row);

    // 5) edge normalization chain
    hipMemsetAsync(norm_col, 0, NN * sizeof(float), stream);
    hipMemsetAsync(deg, 0, NN * sizeof(float), stream);
    const int eb = (EDGES + 255) / 256;
    scatter_norm_col<<<eb, 256, 0, stream>>>(vals, inds, norm_col);
    values_and_deg<<<eb, 256, 0, stream>>>(vals, inds, norm_row, norm_col, vrelu, deg);
    compute_dinv<<<(NN + 255) / 256, 256, 0, stream>>>(deg, dinv);

    // 6) scatter symmetric normalized edges into the (already zeroed) output
    scatter_out<<<eb, 256, 0, stream>>>(vrelu, inds, dinv, out);
}

// Round 8
// 541.875 us; speedup vs baseline: 3.4331x; 1.1774x over previous
//
#include <hip/hip_runtime.h>
#include <hip/hip_bf16.h>
#include <math.h>

// Problem constants (reference: N=10000, D=512, k=30 -> k+1=31 neighbors incl. self)
#define NN 10000
#define DD 512
#define KK 31
#define NCTGT 48            // min candidates (threshold target; margin vs bf16 noise+quant)
#define NCMAX 128           // candidate capacity per row
#define EDGES (NN * KK)     // 310000

typedef __attribute__((ext_vector_type(8))) short short8v;   // 8 bf16 (4 VGPRs)
typedef __attribute__((ext_vector_type(4))) short short4v;   // 4 bf16 (2 VGPRs)
typedef __attribute__((ext_vector_type(4))) float f32x4;     // MFMA C/D frag

__device__ inline unsigned short f32_to_bf16_rne(float f) {
    unsigned u = __float_as_uint(f);
    u += 0x7FFFu + ((u >> 16) & 1u);   // round-to-nearest-even
    return (unsigned short)(u >> 16);
}

// monotone order-preserving map of bf16 bit pattern (u16) -> u16
__device__ inline unsigned mono16(unsigned u) {
    return (u & 0x8000u) ? (0xFFFFu & ~u) : (u | 0x8000u);
}

// ---------------------------------------------------------------------------
// Kernel 1: row L2-normalize x; emit bf16(xn) and the f64 inverse norm.
// ---------------------------------------------------------------------------
__global__ __launch_bounds__(256) void normalize_rows(const float* __restrict__ x,
                                                      unsigned short* __restrict__ xh,
                                                      double* __restrict__ invn) {
    const int row = blockIdx.x;
    const int tid = threadIdx.x;
    const float* xr = x + (size_t)row * DD;
    const float v0 = xr[tid];
    const float v1 = xr[tid + 256];
    double ss = (double)v0 * (double)v0 + (double)v1 * (double)v1;
    #pragma unroll
    for (int off = 32; off > 0; off >>= 1) ss += __shfl_down(ss, off);
    __shared__ double wsum[4];
    __shared__ double sinv;
    if ((tid & 63) == 0) wsum[tid >> 6] = ss;
    __syncthreads();
    if (tid == 0) {
        const double iv = 1.0 / sqrt(wsum[0] + wsum[1] + wsum[2] + wsum[3]);
        invn[row] = iv;
        sinv = iv;
    }
    __syncthreads();
    const float nv = (float)sinv;
    xh[(size_t)row * DD + tid]       = f32_to_bf16_rne(v0 * nv);
    xh[(size_t)row * DD + tid + 256] = f32_to_bf16_rne(v1 * nv);
}

// ---------------------------------------------------------------------------
// Kernel 2: SYMMETRIC simsb(bf16) = bf16(xn) * bf16(xn)^T.  Only upper-tri
// tiles (bi<=bj) are computed: MFMA gives D[r][c]==D[c][r] bit-exact (same
// K-summation tree), so each off-diagonal tile is mirrored via an
// XOR-swizzled LDS transpose (reusing the 32KB staging LDS) + coalesced
// short8 stores.  Halves MFMA work and A/B fetch; C-write bytes unchanged.
// ---------------------------------------------------------------------------
#define TILE 128
#define BKK 64
#define GDIM 79                         // ceil(10000/128)
#define NTRI (GDIM * (GDIM + 1) / 2)    // 3160 upper-tri tiles (= 8 * 395)

__global__ __launch_bounds__(256) void gemm_mfma(const unsigned short* __restrict__ hi,
                                                 unsigned short* __restrict__ outb) {
    __shared__ unsigned short lds[2][TILE * BKK];   // staging 2x16KB; reused as 128x128 T

    // bijective XCD swizzle: 3160 = 8 * 395 exactly
    const int orig = blockIdx.x;
    const int nw = (orig & 7) * (NTRI / 8) + (orig >> 3);
    // triangular row-major enumeration: nw -> (bi, bj), bi<=bj
    int bi = (int)((159.0 - sqrt(25281.0 - 8.0 * (double)nw)) * 0.5);
    while (GDIM * (bi + 1) - ((bi + 1) * bi) / 2 <= nw) ++bi;
    while (GDIM * bi - (bi * (bi - 1)) / 2 > nw) --bi;
    const int bj = bi + (nw - (GDIM * bi - (bi * (bi - 1)) / 2));

    const int row0 = bi * TILE, col0 = bj * TILE;
    const int tid = threadIdx.x;
    const int l = tid & 63, wid = tid >> 6;
    const int wm = wid >> 1, wn = wid & 1;       // 2x2 wave grid
    const int c = l & 15, g = l >> 4;            // frag col / k-group

    f32x4 acc[4][4];
    #pragma unroll
    for (int i = 0; i < 4; ++i)
        #pragma unroll
        for (int j = 0; j < 4; ++j) acc[i][j] = (f32x4){0.f, 0.f, 0.f, 0.f};

    for (int k0 = 0; k0 < DD; k0 += BKK) {
        #pragma unroll
        for (int i = 0; i < 4; ++i) {
            const int s = i * 256 + tid;         // slot id
            const int r = s >> 3;                // row in tile (0..127)
            const int cs = s & 7;                // 16B k-chunk (0..7)
            const int ldso = r * BKK + ((cs ^ (r & 7)) * 8);
            const int gar = row0 + r, gbr = col0 + r;
            short8v ah = (short8v)0, bh = (short8v)0;
            const size_t goff = (size_t)(k0 + cs * 8);
            if (gar < NN) ah = *(const short8v*)(hi + (size_t)gar * DD + goff);
            if (gbr < NN) bh = *(const short8v*)(hi + (size_t)gbr * DD + goff);
            *(short8v*)(&lds[0][ldso]) = ah;
            *(short8v*)(&lds[1][ldso]) = bh;
        }
        __syncthreads();

        #pragma unroll
        for (int ks = 0; ks < 2; ++ks) {
            short8v a_hi[4], b_hi[4];
            const int kc = ks * 4 + g;
            #pragma unroll
            for (int fm = 0; fm < 4; ++fm) {
                const int r = wm * 64 + fm * 16 + c;
                a_hi[fm] = *(const short8v*)(&lds[0][r * BKK + ((kc ^ (r & 7)) * 8)]);
            }
            #pragma unroll
            for (int fn = 0; fn < 4; ++fn) {
                const int r = wn * 64 + fn * 16 + c;
                b_hi[fn] = *(const short8v*)(&lds[1][r * BKK + ((kc ^ (r & 7)) * 8)]);
            }
            #pragma unroll
            for (int fm = 0; fm < 4; ++fm)
                #pragma unroll
                for (int fn = 0; fn < 4; ++fn)
                    acc[fm][fn] = __builtin_amdgcn_mfma_f32_16x16x32_bf16(
                        a_hi[fm], b_hi[fn], acc[fm][fn], 0, 0, 0);
        }
        __syncthreads();
    }

    // ---- epilogue A: normal bf16 store of tile (bi,bj) ----
    #pragma unroll
    for (int fm = 0; fm < 4; ++fm) {
        #pragma unroll
        for (int fn = 0; fn < 4; ++fn) {
            const int gc = col0 + wn * 64 + fn * 16 + c;
            if (gc >= NN) continue;
            #pragma unroll
            for (int r = 0; r < 4; ++r) {
                const int gr = row0 + wm * 64 + fm * 16 + g * 4 + r;
                if (gr < NN) outb[(size_t)gr * NN + gc] = f32_to_bf16_rne(acc[fm][fn][r]);
            }
        }
    }

    // ---- epilogue B: mirrored store of tile (bj,bi) via LDS transpose ----
    if (bi != bj) {
        unsigned short* T = &lds[0][0];   // 128x128 u16 = 32KB (staging reuse)
        #pragma unroll
        for (int fm = 0; fm < 4; ++fm) {
            #pragma unroll
            for (int fn = 0; fn < 4; ++fn) {
                const int cl = wn * 64 + fn * 16 + c;
                const int rl = wm * 64 + fm * 16 + g * 4;
                short4v pk;
                #pragma unroll
                for (int r = 0; r < 4; ++r)
                    pk[r] = (short)f32_to_bf16_rne(acc[fm][fn][r]);
                *(short4v*)(&T[cl * TILE + (rl ^ ((cl & 7) << 3))]) = pk;
            }
        }
        __syncthreads();
        #pragma unroll
        for (int it = 0; it < 8; ++it) {
            const int s = tid + it * 256;      // 2048 chunks of 8 u16
            const int cT = s >> 4;             // 0..127 (output row - col0)
            const int rb = (s & 15) * 8;       // 0..120 (output col - row0)
            const short8v v = *(const short8v*)(&T[cT * TILE + (rb ^ ((cT & 7) << 3))]);
            const int orow = col0 + cT;
            const int ocol = row0 + rb;
            if (orow < NN) {
                if (ocol + 8 <= NN) {
                    *(short8v*)(outb + (size_t)orow * NN + ocol) = v;
                } else {
                    #pragma unroll
                    for (int e = 0; e < 8; ++e)
                        if (ocol + e < NN)
                            outb[(size_t)orow * NN + ocol + e] = (unsigned short)v[e];
                }
            }
        }
    }
}

// ---------------------------------------------------------------------------
// Kernel 3: per-row candidate selection via register-resident BINARY SEARCH
// on the 16-bit monotone map (no LDS histogram -> no atomic serialization,
// tiny LDS -> 8 blocks/CU).  Each thread holds 40 mono16 values packed in 20
// VGPRs.  16 iterations find the exact largest threshold with count >= NCTGT.
// Then compact indices >= threshold and zero-fill the f32 output row (fused).
// ---------------------------------------------------------------------------
__global__ __launch_bounds__(256) void topk_select(const unsigned short* __restrict__ simsb,
                                                   float* __restrict__ out,
                                                   int* __restrict__ cinds,
                                                   int* __restrict__ ccnt) {
    const int row = blockIdx.x;
    const int tid = threadIdx.x;
    const uint4* s4 = (const uint4*)(simsb + (size_t)row * NN);

    // load 5 x uint4 (8 bf16 each), mono-map and repack (2 mono16 per u32)
    unsigned m[20];
    #pragma unroll
    for (int p = 0; p < 5; ++p) {
        const int i = tid + p * 256;
        const bool ok = (i < NN / 8);            // 1250 chunks exactly
        uint4 v = ok ? s4[i] : make_uint4(0u, 0u, 0u, 0u);
        const unsigned w[4] = {v.x, v.y, v.z, v.w};
        #pragma unroll
        for (int e = 0; e < 4; ++e) {
            unsigned lo16 = mono16(w[e] & 0xFFFFu);
            unsigned hi16 = mono16(w[e] >> 16);
            if (!ok) { lo16 = 0u; hi16 = 0u; }   // pad: never selected
            m[p * 4 + e] = lo16 | (hi16 << 16);
        }
    }

    // binary search for largest t with count(mono >= t) >= NCTGT
    __shared__ unsigned wcnt[16][4];
    unsigned lo = 0u, hi = 65536u;
    #pragma unroll
    for (int it = 0; it < 16; ++it) {
        const unsigned mid = (lo + hi) >> 1;
        unsigned cnt = 0u;
        #pragma unroll
        for (int q = 0; q < 20; ++q) {
            cnt += ((m[q] & 0xFFFFu) >= mid) ? 1u : 0u;
            cnt += ((m[q] >> 16) >= mid) ? 1u : 0u;
        }
        #pragma unroll
        for (int off = 32; off > 0; off >>= 1) cnt += __shfl_down(cnt, off);
        if ((tid & 63) == 0) wcnt[it][tid >> 6] = cnt;
        __syncthreads();
        const unsigned total = wcnt[it][0] + wcnt[it][1] + wcnt[it][2] + wcnt[it][3];
        if (total >= NCTGT) lo = mid; else hi = mid;
    }
    const unsigned mthresh = lo;

    __shared__ unsigned cnt_sh;
    if (tid == 0) cnt_sh = 0u;
    __syncthreads();

    // compact (order nondeterministic; rescore re-ranks deterministically)
    #pragma unroll
    for (int p = 0; p < 5; ++p) {
        const int i = tid + p * 256;
        #pragma unroll
        for (int e = 0; e < 4; ++e) {
            const unsigned mm = m[p * 4 + e];
            if ((mm & 0xFFFFu) >= mthresh) {
                const unsigned pos = atomicAdd(&cnt_sh, 1u);
                if (pos < NCMAX) cinds[(size_t)row * NCMAX + pos] = i * 8 + e * 2;
            }
            if ((mm >> 16) >= mthresh) {
                const unsigned pos = atomicAdd(&cnt_sh, 1u);
                if (pos < NCMAX) cinds[(size_t)row * NCMAX + pos] = i * 8 + e * 2 + 1;
            }
        }
    }

    // fused zero-fill of the f32 output row (row-exclusive, race-free)
    float4* o4 = (float4*)(out + (size_t)row * NN);
    const float4 zero4 = make_float4(0.f, 0.f, 0.f, 0.f);
    for (int i = tid; i < NN / 4; i += 256) o4[i] = zero4;

    __syncthreads();
    if (tid == 0) ccnt[row] = (int)(cnt_sh < NCMAX ? cnt_sh : NCMAX);
}

// ---------------------------------------------------------------------------
// Kernel 4: f64 rescore of the candidates; exact deterministic re-ranking by
// (value desc, index asc); emits final 31 (vals f32, inds) + norm_row.
// ---------------------------------------------------------------------------
__global__ __launch_bounds__(256) void rescore_topk(const float* __restrict__ x,
                                                    const double* __restrict__ invn,
                                                    const int* __restrict__ cinds,
                                                    const int* __restrict__ ccnt,
                                                    float* __restrict__ vals,
                                                    int* __restrict__ inds,
                                                    float* __restrict__ norm_row) {
    const int row = blockIdx.x;
    const int tid = threadIdx.x;
    const int lane = tid & 63;
    const int wave = tid >> 6;
    const int cnt = ccnt[row];

    __shared__ double scand[NCMAX];
    __shared__ int    scidx[NCMAX];
    __shared__ float  topv[KK];

    if (tid < cnt) scidx[tid] = cinds[(size_t)row * NCMAX + tid];
    __syncthreads();

    const float* xr = x + (size_t)row * DD;
    float a[8];
    #pragma unroll
    for (int t = 0; t < 8; ++t) a[t] = xr[lane * 8 + t];
    const double ir = invn[row];

    for (int cc = wave; cc < cnt; cc += 4) {
        const int j = scidx[cc];
        const float* xj = x + (size_t)j * DD;
        double p = 0.0;
        #pragma unroll
        for (int t = 0; t < 8; ++t)
            p = fma((double)a[t], (double)xj[lane * 8 + t], p);
        #pragma unroll
        for (int off = 32; off > 0; off >>= 1)
            p += __shfl_down(p, off);
        if (lane == 0) scand[cc] = p * ir * invn[j];
    }
    __syncthreads();

    if (tid < cnt) {
        const double v = scand[tid];
        const int idx = scidx[tid];
        int rank = 0;
        for (int mm = 0; mm < cnt; ++mm) {
            const double vm = scand[mm];
            const int im = scidx[mm];
            if (vm > v || (vm == v && im < idx)) ++rank;
        }
        if (rank < KK) {
            const float vf = (float)v;
            vals[(size_t)row * KK + rank] = vf;
            inds[(size_t)row * KK + rank] = idx;
            topv[rank] = vf;
        }
    }
    __syncthreads();
    if (tid < 64) {
        float contrib = (tid < KK) ? topv[tid] : 0.f;
        #pragma unroll
        for (int off = 32; off > 0; off >>= 1)
            contrib += __shfl_down(contrib, off);
        if (tid == 0) norm_row[row] = contrib;
    }
}

// ---------------------------------------------------------------------------
// Edge-chain kernels (310k edges each, trivial cost)
// ---------------------------------------------------------------------------
__global__ void scatter_norm_col(const float* __restrict__ vals,
                                 const int* __restrict__ inds,
                                 float* __restrict__ norm_col) {
    const int e = blockIdx.x * 256 + threadIdx.x;
    if (e >= EDGES) return;
    atomicAdd(&norm_col[inds[e]], vals[e]);
}

__global__ void values_and_deg(const float* __restrict__ vals,
                               const int* __restrict__ inds,
                               const float* __restrict__ norm_row,
                               const float* __restrict__ norm_col,
                               float* __restrict__ vrelu,
                               float* __restrict__ deg) {
    const int e = blockIdx.x * 256 + threadIdx.x;
    if (e >= EDGES) return;
    const int i = e / KK;
    const int j = inds[e];
    const float ni = norm_row[i] + norm_col[i];
    const float nj = norm_row[j] + norm_col[j];
    float v = vals[e] * (1.0f / sqrtf(ni)) * (1.0f / sqrtf(nj));
    if (v != v) v = 0.f;           // NaN -> 0
    v = fmaxf(v, 0.f);             // relu (both symmetric copies)
    vrelu[e] = v;
    atomicAdd(&deg[i], v);
    atomicAdd(&deg[j], v);
}

__global__ void compute_dinv(const float* __restrict__ deg, float* __restrict__ dinv) {
    const int i = blockIdx.x * 256 + threadIdx.x;
    if (i >= NN) return;
    float di = 1.0f / sqrtf(deg[i]);
    if (!isfinite(di)) di = 0.f;
    dinv[i] = di;
}

__global__ void scatter_out(const float* __restrict__ vrelu,
                            const int* __restrict__ inds,
                            const float* __restrict__ dinv,
                            float* __restrict__ out) {
    const int e = blockIdx.x * 256 + threadIdx.x;
    if (e >= EDGES) return;
    const int i = e / KK;
    const int j = inds[e];
    const float nv = vrelu[e] * dinv[i] * dinv[j];
    atomicAdd(&out[(size_t)i * NN + j], nv);
    atomicAdd(&out[(size_t)j * NN + i], nv);
}

// ---------------------------------------------------------------------------
// Launch
// ---------------------------------------------------------------------------
extern "C" void kernel_launch(void* const* d_in, const int* in_sizes, int n_in,
                              void* d_out, int out_size, void* d_ws, size_t ws_size,
                              hipStream_t stream) {
    const float* x = (const float*)d_in[0];
    float* out = (float*)d_out;
    float* ws = (float*)d_ws;

    // workspace layout (f32-element offsets), total ~219.4 MB (ws_size ~1.6 GB)
    unsigned short* simsb = (unsigned short*)ws;              // 100,000,000 u16 -> 50,000,000 slots
    unsigned short* xh    = (unsigned short*)(ws + 50000000); // 5,120,000 u16 -> 2,560,000 slots
    double* invn          = (double*)(ws + 52560000);         // 10,000 f64 (20,000 slots, 8B-aligned)
    int*    cinds         = (int*)(ws + 52580000);            // 10,000 x 128 = 1,280,000
    int*    ccnt          = (int*)(ws + 53860000);            // 10,000
    float*  vals          = ws + 53870000;                    // 310,000
    int*    inds          = (int*)(ws + 54180000);            // 310,000
    float*  norm_row      = ws + 54490000;                    // 10,000
    float*  norm_col      = ws + 54500000;                    // 10,000
    float*  deg           = ws + 54510000;                    // 10,000
    float*  dinv          = ws + 54520000;                    // 10,000
    float*  vrelu         = ws + 54530000;                    // 310,000

    // 1) row normalize -> bf16 + f64 inv norms
    normalize_rows<<<NN, 256, 0, stream>>>(x, xh, invn);

    // 2) bf16 sims (symmetric: upper-tri tiles + mirrored store)
    gemm_mfma<<<NTRI, 256, 0, stream>>>(xh, simsb);

    // 3) per-row candidate superset via binary-search select + zero d_out
    topk_select<<<NN, 256, 0, stream>>>(simsb, out, cinds, ccnt);

    // 4) exact f64 rescore + final top-31 selection
    rescore_topk<<<NN, 256, 0, stream>>>(x, invn, cinds, ccnt, vals, inds, norm_row);

    // 5) edge normalization chain
    hipMemsetAsync(norm_col, 0, NN * sizeof(float), stream);
    hipMemsetAsync(deg, 0, NN * sizeof(float), stream);
    const int eb = (EDGES + 255) / 256;
    scatter_norm_col<<<eb, 256, 0, stream>>>(vals, inds, norm_col);
    values_and_deg<<<eb, 256, 0, stream>>>(vals, inds, norm_row, norm_col, vrelu, deg);
    compute_dinv<<<(NN + 255) / 256, 256, 0, stream>>>(deg, dinv);

    // 6) scatter symmetric normalized edges into the (already zeroed) output
    scatter_out<<<eb, 256, 0, stream>>>(vrelu, inds, dinv, out);
}